// Round 2
// baseline (2389.764 us; speedup 1.0000x reference)
//
#include <hip/hip_runtime.h>
#include <cstdint>
#include <cstddef>

#define DEV __device__ __forceinline__

constexpr int N_  = 16384;
constexpr int D_  = 1024;
constexpr int E_  = 65536;
constexpr int ET_ = E_ + N_;   // 81920 edges incl. self loops
constexpr int H_  = 8;
constexpr int C_  = 512;
constexpr int F_  = 4096;      // H_*C_
constexpr unsigned ORD_NEG = 0x007FFFFFu; // f2ord(-inf)

// ---------- helpers ----------
DEV unsigned short f2bf(float f){
  unsigned u = __float_as_uint(f);
  unsigned r = u + 0x7FFFu + ((u >> 16) & 1u); // RNE
  return (unsigned short)(r >> 16);
}
DEV float bf2f_lo(unsigned u){ return __uint_as_float(u << 16); }
DEV float bf2f_hi(unsigned u){ return __uint_as_float(u & 0xFFFF0000u); }
DEV unsigned pack2bf(float lo, float hi){
  return (unsigned)f2bf(lo) | ((unsigned)f2bf(hi) << 16);
}
DEV unsigned f2ord(float f){
  unsigned u = __float_as_uint(f);
  return (u & 0x80000000u) ? ~u : (u | 0x80000000u);
}
DEV float ord2f(unsigned u){
  return (u & 0x80000000u) ? __uint_as_float(u ^ 0x80000000u) : __uint_as_float(~u);
}
DEV float lrelu(float x){ return x >= 0.f ? x : 0.2f * x; }
DEV float waveSum(float v){
  #pragma unroll
  for (int o = 32; o > 0; o >>= 1) v += __shfl_xor(v, o);
  return v;
}
DEV int eSRC(const int* ei, int e){ return e < E_ ? ei[e]      : e - E_; }
DEV int eDST(const int* ei, int e){ return e < E_ ? ei[E_ + e] : e - E_; }

// ---------- precompute ----------
// wvec[d][j] : j<8 -> sum_c W1s[d, j*512+c]*a1s[j,c] ; j>=8 -> same with W1d,a1d
__global__ __launch_bounds__(256) void build_wvec1(
    const float* __restrict__ W1s, const float* __restrict__ W1d,
    const float* __restrict__ a1s, const float* __restrict__ a1d,
    float* __restrict__ wvec){
  int t = threadIdx.x;
  int id = blockIdx.x * 4 + (t >> 6);
  int lane = t & 63;
  int d = id >> 4, j = id & 15;
  const float* Wp = (j < 8) ? W1s : W1d;
  const float* ap = (j < 8) ? a1s : a1d;
  int hh = j & 7;
  float s = 0.f;
  #pragma unroll
  for (int i = 0; i < C_ / 64; i++){
    int c = i * 64 + lane;
    s += Wp[(size_t)d * F_ + hh * C_ + c] * ap[hh * C_ + c];
  }
  s = waveSum(s);
  if (lane == 0) wvec[d * 16 + j] = s;
}

__global__ void build_wd2(const float* __restrict__ W2d, const float* __restrict__ a2d,
                          float* __restrict__ wd2){
  int k = blockIdx.x * blockDim.x + threadIdx.x;
  if (k < F_) wd2[k] = W2d[k * 2] * a2d[0] + W2d[k * 2 + 1] * a2d[1];
}

__global__ void init_buffers(unsigned* __restrict__ m1, float* __restrict__ den1,
                             unsigned* __restrict__ m2, float* __restrict__ den2,
                             int* __restrict__ cnt, float* __restrict__ s0a,
                             float* __restrict__ s1a, float* __restrict__ sda){
  int i = blockIdx.x * blockDim.x + threadIdx.x;
  if (i < N_ * H_){ m1[i] = ORD_NEG; den1[i] = 0.f; }
  if (i < N_){ m2[i] = ORD_NEG; den2[i] = 0.f; cnt[i] = 0;
               s0a[i] = 0.f; s1a[i] = 0.f; sda[i] = 0.f; }
}

// ---------- al_s1/al_d1 = x @ wvec  (16 dots of length 1024 per node) ----------
__global__ __launch_bounds__(256) void al_build(const float* __restrict__ X,
                                                const float* __restrict__ wvec,
                                                float* __restrict__ al_s,
                                                float* __restrict__ al_d){
  int t = threadIdx.x;
  int n = blockIdx.x * 4 + (t >> 6);
  int lane = t & 63;
  float acc[16] = {};
  for (int i = 0; i < D_ / 64; i++){
    int d = i * 64 + lane;
    float xv = X[(size_t)n * D_ + d];
    const float4* wp = reinterpret_cast<const float4*>(wvec + d * 16);
    float4 w0 = wp[0], w1 = wp[1], w2 = wp[2], w3 = wp[3];
    acc[0] += xv*w0.x; acc[1] += xv*w0.y; acc[2]  += xv*w0.z; acc[3]  += xv*w0.w;
    acc[4] += xv*w1.x; acc[5] += xv*w1.y; acc[6]  += xv*w1.z; acc[7]  += xv*w1.w;
    acc[8] += xv*w2.x; acc[9] += xv*w2.y; acc[10] += xv*w2.z; acc[11] += xv*w2.w;
    acc[12]+= xv*w3.x; acc[13]+= xv*w3.y; acc[14] += xv*w3.z; acc[15] += xv*w3.w;
  }
  #pragma unroll
  for (int j = 0; j < 16; j++){
    float s = waveSum(acc[j]);
    if (lane == 0){
      if (j < 8) al_s[n * 8 + j] = s;
      else       al_d[n * 8 + (j - 8)] = s;
    }
  }
}

// ---------- layer-1 edge softmax ----------
__global__ void edge_max1(const int* __restrict__ ei, const float* __restrict__ al_s,
                          const float* __restrict__ al_d, unsigned* __restrict__ m1){
  int t = blockIdx.x * blockDim.x + threadIdx.x;
  if (t >= ET_ * H_) return;
  int e = t >> 3, hh = t & 7;
  int s = eSRC(ei, e), dd = eDST(ei, e);
  float lg = lrelu(al_s[s * 8 + hh] + al_d[dd * 8 + hh]);
  atomicMax(&m1[dd * 8 + hh], f2ord(lg));
}

__global__ void edge_exp1(const int* __restrict__ ei, const float* __restrict__ al_s,
                          const float* __restrict__ al_d, const unsigned* __restrict__ m1,
                          float* __restrict__ den1, float* __restrict__ expv){
  int t = blockIdx.x * blockDim.x + threadIdx.x;
  if (t >= ET_ * H_) return;
  int e = t >> 3, hh = t & 7;
  int s = eSRC(ei, e), dd = eDST(ei, e);
  float lg = lrelu(al_s[s * 8 + hh] + al_d[dd * 8 + hh]);
  float mv = ord2f(m1[dd * 8 + hh]);
  if (mv < -3.0e38f) mv = 0.f;
  float ev = expf(lg - mv);
  expv[e * 8 + hh] = ev;
  atomicAdd(&den1[dd * 8 + hh], ev);
}

// ---------- CSR build ----------
__global__ void edge_hist(const int* __restrict__ ei, int* __restrict__ cnt){
  int e = blockIdx.x * blockDim.x + threadIdx.x;
  if (e < ET_) atomicAdd(&cnt[eDST(ei, e)], 1);
}

__global__ __launch_bounds__(1024) void scan_kernel(const int* __restrict__ cnt,
                                                    int* __restrict__ off,
                                                    int* __restrict__ cur){
  __shared__ int sums[1024];
  int t = threadIdx.x;
  int base = t * 16;
  int loc[16]; int s = 0;
  #pragma unroll
  for (int i = 0; i < 16; i++){ loc[i] = s; s += cnt[base + i]; }
  sums[t] = s;
  __syncthreads();
  for (int o = 1; o < 1024; o <<= 1){
    int v = (t >= o) ? sums[t - o] : 0;
    __syncthreads();
    sums[t] += v;
    __syncthreads();
  }
  int prefix = sums[t] - s;
  #pragma unroll
  for (int i = 0; i < 16; i++){ off[base + i] = prefix + loc[i]; cur[base + i] = prefix + loc[i]; }
  if (t == 1023) off[N_] = prefix + s;
}

__global__ void edge_scatter(const int* __restrict__ ei, int* __restrict__ cur,
                             int* __restrict__ eid, int* __restrict__ srcs){
  int e = blockIdx.x * blockDim.x + threadIdx.x;
  if (e >= ET_) return;
  int dd = eDST(ei, e);
  int p = atomicAdd(&cur[dd], 1);
  eid[p] = e; srcs[p] = eSRC(ei, e);
}

// ---------- per-head fp32 GEMM: hs_head = x @ W1s[:, hh*512 .. +512), bf16 out ----------
__global__ __launch_bounds__(256) void gemm_head(const float* __restrict__ X,
                                                 const float* __restrict__ W,
                                                 unsigned short* __restrict__ out,
                                                 int colBase){
  __shared__ float sA[16][68];
  __shared__ float sB[16][68];
  int t = threadIdx.x;
  int bm = blockIdx.y * 64;
  int bn = blockIdx.x * 64;
  int am  = t >> 2,        akq = (t & 3) * 4;
  int bk  = t >> 4,        bnq = (t & 15) * 4;
  int row0 = (t >> 4) * 4, col0 = (t & 15) * 4;
  float acc[4][4] = {};
  for (int k0 = 0; k0 < D_; k0 += 16){
    float4 av = *reinterpret_cast<const float4*>(X + (size_t)(bm + am) * D_ + k0 + akq);
    float4 bv = *reinterpret_cast<const float4*>(W + (size_t)(k0 + bk) * F_ + colBase + bn + bnq);
    __syncthreads();
    sA[akq + 0][am] = av.x; sA[akq + 1][am] = av.y;
    sA[akq + 2][am] = av.z; sA[akq + 3][am] = av.w;
    *reinterpret_cast<float4*>(&sB[bk][bnq]) = bv;
    __syncthreads();
    #pragma unroll
    for (int kk = 0; kk < 16; kk++){
      float4 a = *reinterpret_cast<const float4*>(&sA[kk][row0]);
      float4 b = *reinterpret_cast<const float4*>(&sB[kk][col0]);
      acc[0][0] += a.x*b.x; acc[0][1] += a.x*b.y; acc[0][2] += a.x*b.z; acc[0][3] += a.x*b.w;
      acc[1][0] += a.y*b.x; acc[1][1] += a.y*b.y; acc[1][2] += a.y*b.z; acc[1][3] += a.y*b.w;
      acc[2][0] += a.z*b.x; acc[2][1] += a.z*b.y; acc[2][2] += a.z*b.z; acc[2][3] += a.z*b.w;
      acc[3][0] += a.w*b.x; acc[3][1] += a.w*b.y; acc[3][2] += a.w*b.z; acc[3][3] += a.w*b.w;
    }
  }
  #pragma unroll
  for (int i = 0; i < 4; i++){
    size_t r = (size_t)(bm + row0 + i) * C_ + bn + col0;
    uint2 o;
    o.x = pack2bf(acc[i][0], acc[i][1]);
    o.y = pack2bf(acc[i][2], acc[i][3]);
    *reinterpret_cast<uint2*>(out + r) = o;
  }
}

// ---------- per-head aggregation fused with layer-2 dot products ----------
// one wave per node: aggregate 512 channels over incident edges, add b1 slice,
// then accumulate s0 += h.W2s[:,0], s1 += h.W2s[:,1], sd += h.wd2
__global__ __launch_bounds__(256) void agg_head(
    const unsigned short* __restrict__ hsH, const float* __restrict__ expv,
    const float* __restrict__ den1, const int* __restrict__ off,
    const int* __restrict__ eid, const int* __restrict__ srcs,
    const float* __restrict__ b1, const float* __restrict__ W2s,
    const float* __restrict__ wd2, int hh,
    float* __restrict__ s0a, float* __restrict__ s1a, float* __restrict__ sda){
  int t = threadIdx.x;
  int n = blockIdx.x * 4 + (t >> 6);
  int lane = t & 63;
  int c0 = lane * 8;                     // channel within head
  float inv = 1.f / (den1[n * 8 + hh] + 1e-16f);
  float acc[8] = {};
  int i0 = off[n], i1 = off[n + 1];
  for (int i = i0; i < i1; i++){
    int e = eid[i]; int s = srcs[i];
    float a = expv[e * 8 + hh] * inv;
    uint4 v = *reinterpret_cast<const uint4*>(hsH + (size_t)s * C_ + c0);
    acc[0] += a * bf2f_lo(v.x); acc[1] += a * bf2f_hi(v.x);
    acc[2] += a * bf2f_lo(v.y); acc[3] += a * bf2f_hi(v.y);
    acc[4] += a * bf2f_lo(v.z); acc[5] += a * bf2f_hi(v.z);
    acc[6] += a * bf2f_lo(v.w); acc[7] += a * bf2f_hi(v.w);
  }
  int gc = hh * C_ + c0;                 // global channel
  float4 bb0 = *reinterpret_cast<const float4*>(b1 + gc);
  float4 bb1 = *reinterpret_cast<const float4*>(b1 + gc + 4);
  acc[0] += bb0.x; acc[1] += bb0.y; acc[2] += bb0.z; acc[3] += bb0.w;
  acc[4] += bb1.x; acc[5] += bb1.y; acc[6] += bb1.z; acc[7] += bb1.w;
  float s0 = 0.f, s1 = 0.f, sd = 0.f;
  #pragma unroll
  for (int j = 0; j < 8; j++){
    float2 w = *reinterpret_cast<const float2*>(W2s + (size_t)(gc + j) * 2);
    s0 += acc[j] * w.x; s1 += acc[j] * w.y; sd += acc[j] * wd2[gc + j];
  }
  s0 = waveSum(s0); s1 = waveSum(s1); sd = waveSum(sd);
  if (lane == 0){
    s0a[n] += s0; s1a[n] += s1; sda[n] += sd;
  }
}

// ---------- layer-2 attention logits ----------
__global__ void finalize_l2(const float* __restrict__ s0a, const float* __restrict__ s1a,
                            const float* __restrict__ sda, const float* __restrict__ a2s,
                            float* __restrict__ als2, float* __restrict__ ald2){
  int n = blockIdx.x * blockDim.x + threadIdx.x;
  if (n >= N_) return;
  als2[n] = s0a[n] * a2s[0] + s1a[n] * a2s[1];
  ald2[n] = sda[n];
}

__global__ void edge_max2(const int* __restrict__ ei, const float* __restrict__ als2,
                          const float* __restrict__ ald2, unsigned* __restrict__ m2){
  int e = blockIdx.x * blockDim.x + threadIdx.x;
  if (e >= ET_) return;
  int dd = eDST(ei, e);
  float lg = lrelu(als2[eSRC(ei, e)] + ald2[dd]);
  atomicMax(&m2[dd], f2ord(lg));
}

__global__ void edge_exp2(const int* __restrict__ ei, const float* __restrict__ als2,
                          const float* __restrict__ ald2, const unsigned* __restrict__ m2,
                          float* __restrict__ den2, float* __restrict__ expv2){
  int e = blockIdx.x * blockDim.x + threadIdx.x;
  if (e >= ET_) return;
  int dd = eDST(ei, e);
  float lg = lrelu(als2[eSRC(ei, e)] + ald2[dd]);
  float mv = ord2f(m2[dd]);
  if (mv < -3.0e38f) mv = 0.f;
  float ev = expf(lg - mv);
  expv2[e] = ev;
  atomicAdd(&den2[dd], ev);
}

__global__ void aggregate2(const float* __restrict__ s0a, const float* __restrict__ s1a,
    const float* __restrict__ expv2, const float* __restrict__ den2,
    const int* __restrict__ off, const int* __restrict__ eid, const int* __restrict__ srcs,
    const float* __restrict__ b2, float* __restrict__ out){
  int n = blockIdx.x * blockDim.x + threadIdx.x;
  if (n >= N_) return;
  float inv = 1.f / (den2[n] + 1e-16f);
  float a0 = 0.f, a1 = 0.f;
  int i1 = off[n + 1];
  for (int i = off[n]; i < i1; i++){
    int e = eid[i], s = srcs[i];
    float a = expv2[e] * inv;
    a0 += a * s0a[s]; a1 += a * s1a[s];
  }
  out[2 * n]     = a0 + b2[0];
  out[2 * n + 1] = a1 + b2[1];
}

// ---------- host ----------
extern "C" void kernel_launch(void* const* d_in, const int* in_sizes, int n_in,
                              void* d_out, int out_size, void* d_ws, size_t ws_size,
                              hipStream_t stream){
  const float* x   = (const float*)d_in[0];
  const int*   ei  = (const int*)  d_in[1];
  const float* W1s = (const float*)d_in[2];
  const float* W1d = (const float*)d_in[3];
  const float* a1s = (const float*)d_in[4];
  const float* a1d = (const float*)d_in[5];
  const float* b1  = (const float*)d_in[6];
  const float* W2s = (const float*)d_in[7];
  const float* W2d = (const float*)d_in[8];
  const float* a2s = (const float*)d_in[9];
  const float* a2d = (const float*)d_in[10];
  const float* b2  = (const float*)d_in[11];
  float* out = (float*)d_out;

  char* p = (char*)d_ws;
  auto alloc = [&](size_t bytes) -> void* {
    void* r = (void*)p;
    p += (bytes + 255) & ~(size_t)255;
    return r;
  };
  unsigned short* hsH = (unsigned short*)alloc((size_t)N_ * C_ * 2);  // 16 MB per-head feats
  float* al_s1 = (float*)alloc((size_t)N_ * H_ * 4);
  float* al_d1 = (float*)alloc((size_t)N_ * H_ * 4);
  float* wvec  = (float*)alloc((size_t)D_ * 16 * 4);
  unsigned* m1 = (unsigned*)alloc((size_t)N_ * H_ * 4);
  float* den1  = (float*)alloc((size_t)N_ * H_ * 4);
  float* expv1 = (float*)alloc((size_t)ET_ * H_ * 4);
  int* cnt  = (int*)alloc((size_t)N_ * 4);
  int* off  = (int*)alloc((size_t)(N_ + 1) * 4);
  int* cur  = (int*)alloc((size_t)N_ * 4);
  int* eid  = (int*)alloc((size_t)ET_ * 4);
  int* srcs = (int*)alloc((size_t)ET_ * 4);
  float* s0a = (float*)alloc((size_t)N_ * 4);
  float* s1a = (float*)alloc((size_t)N_ * 4);
  float* sda = (float*)alloc((size_t)N_ * 4);
  float* wd2 = (float*)alloc((size_t)F_ * 4);
  unsigned* m2 = (unsigned*)alloc((size_t)N_ * 4);
  float* den2  = (float*)alloc((size_t)N_ * 4);
  float* als2  = (float*)alloc((size_t)N_ * 4);
  float* ald2  = (float*)alloc((size_t)N_ * 4);
  float* expv2 = (float*)alloc((size_t)ET_ * 4);
  // total ≈ 23 MB

  // precompute
  build_wvec1<<<dim3(D_ * 16 / 4), dim3(256), 0, stream>>>(W1s, W1d, a1s, a1d, wvec);
  build_wd2<<<dim3(F_ / 256), dim3(256), 0, stream>>>(W2d, a2d, wd2);
  init_buffers<<<dim3(N_ * H_ / 256), dim3(256), 0, stream>>>(m1, den1, m2, den2, cnt,
                                                              s0a, s1a, sda);

  // layer-1 attention logits + softmax
  al_build<<<dim3(N_ / 4), dim3(256), 0, stream>>>(x, wvec, al_s1, al_d1);
  edge_max1<<<dim3(ET_ * H_ / 256), dim3(256), 0, stream>>>(ei, al_s1, al_d1, m1);
  edge_exp1<<<dim3(ET_ * H_ / 256), dim3(256), 0, stream>>>(ei, al_s1, al_d1, m1, den1, expv1);

  // CSR (shared by both layers)
  edge_hist<<<dim3(ET_ / 256), dim3(256), 0, stream>>>(ei, cnt);
  scan_kernel<<<dim3(1), dim3(1024), 0, stream>>>(cnt, off, cur);
  edge_scatter<<<dim3(ET_ / 256), dim3(256), 0, stream>>>(ei, cur, eid, srcs);

  // per-head: GEMM then fused aggregation + layer-2 partial dots
  for (int hh = 0; hh < H_; hh++){
    gemm_head<<<dim3(C_ / 64, N_ / 64), dim3(256), 0, stream>>>(x, W1s, hsH, hh * C_);
    agg_head<<<dim3(N_ / 4), dim3(256), 0, stream>>>(hsH, expv1, den1, off, eid, srcs,
                                                     b1, W2s, wd2, hh, s0a, s1a, sda);
  }

  // layer-2 softmax + aggregation
  finalize_l2<<<dim3(N_ / 256), dim3(256), 0, stream>>>(s0a, s1a, sda, a2s, als2, ald2);
  edge_max2<<<dim3(ET_ / 256), dim3(256), 0, stream>>>(ei, als2, ald2, m2);
  edge_exp2<<<dim3(ET_ / 256), dim3(256), 0, stream>>>(ei, als2, ald2, m2, den2, expv2);
  aggregate2<<<dim3(N_ / 256), dim3(256), 0, stream>>>(s0a, s1a, expv2, den2,
                                                       off, eid, srcs, b2, out);
}

// Round 3
// 517.533 us; speedup vs baseline: 4.6176x; 4.6176x over previous
//
#include <hip/hip_runtime.h>
#include <cstdint>
#include <cstddef>

#define DEV __device__ __forceinline__

typedef unsigned short ushort_t;
typedef __attribute__((ext_vector_type(8))) short bf16x8;
typedef __attribute__((ext_vector_type(4))) float f32x4;

constexpr int N_  = 16384;
constexpr int D_  = 1024;
constexpr int E_  = 65536;
constexpr int ET_ = E_ + N_;   // 81920 edges incl. self loops
constexpr int H_  = 8;
constexpr int C_  = 512;
constexpr int F_  = 4096;      // H_*C_
constexpr unsigned ORD_NEG = 0x007FFFFFu; // f2ord(-inf)

// ---------- helpers ----------
DEV unsigned short f2bf(float f){
  unsigned u = __float_as_uint(f);
  unsigned r = u + 0x7FFFu + ((u >> 16) & 1u); // RNE
  return (unsigned short)(r >> 16);
}
DEV float bf2f_lo(unsigned u){ return __uint_as_float(u << 16); }
DEV float bf2f_hi(unsigned u){ return __uint_as_float(u & 0xFFFF0000u); }
DEV unsigned pack2bf(float lo, float hi){
  return (unsigned)f2bf(lo) | ((unsigned)f2bf(hi) << 16);
}
DEV unsigned f2ord(float f){
  unsigned u = __float_as_uint(f);
  return (u & 0x80000000u) ? ~u : (u | 0x80000000u);
}
DEV float ord2f(unsigned u){
  return (u & 0x80000000u) ? __uint_as_float(u ^ 0x80000000u) : __uint_as_float(~u);
}
DEV float lrelu(float x){ return x >= 0.f ? x : 0.2f * x; }
DEV float waveSum(float v){
  #pragma unroll
  for (int o = 32; o > 0; o >>= 1) v += __shfl_xor(v, o);
  return v;
}
DEV int eSRC(const int* ei, int e){ return e < E_ ? ei[e]      : e - E_; }
DEV int eDST(const int* ei, int e){ return e < E_ ? ei[E_ + e] : e - E_; }

DEV void gl16(const unsigned short* g, unsigned short* l){
  __builtin_amdgcn_global_load_lds(
      (const __attribute__((address_space(1))) void*)g,
      (__attribute__((address_space(3))) void*)l, 16, 0, 0);
}

// ---------- dtype conversions ----------
__global__ void x2bf(const float* __restrict__ X, unsigned short* __restrict__ Xb){
  int i = (blockIdx.x * blockDim.x + threadIdx.x) * 8;
  float4 v0 = *reinterpret_cast<const float4*>(X + i);
  float4 v1 = *reinterpret_cast<const float4*>(X + i + 4);
  uint4 o;
  o.x = pack2bf(v0.x, v0.y); o.y = pack2bf(v0.z, v0.w);
  o.z = pack2bf(v1.x, v1.y); o.w = pack2bf(v1.z, v1.w);
  *reinterpret_cast<uint4*>(Xb + i) = o;
}

// Wt[f][k] = bf16(W1s[k][f])
__global__ __launch_bounds__(1024) void build_wt(const float* __restrict__ W,
                                                 unsigned short* __restrict__ Wt){
  __shared__ float tile[32][33];
  int f0 = blockIdx.x * 32, k0 = blockIdx.y * 32;
  int tx = threadIdx.x & 31, ty = threadIdx.x >> 5;
  tile[ty][tx] = W[(size_t)(k0 + ty) * F_ + f0 + tx];
  __syncthreads();
  Wt[(size_t)(f0 + ty) * D_ + k0 + tx] = f2bf(tile[tx][ty]);
}

// ---------- precompute ----------
__global__ __launch_bounds__(256) void build_wvec1(
    const float* __restrict__ W1s, const float* __restrict__ W1d,
    const float* __restrict__ a1s, const float* __restrict__ a1d,
    float* __restrict__ wvec){
  int t = threadIdx.x;
  int id = blockIdx.x * 4 + (t >> 6);
  int lane = t & 63;
  int d = id >> 4, j = id & 15;
  const float* Wp = (j < 8) ? W1s : W1d;
  const float* ap = (j < 8) ? a1s : a1d;
  int hh = j & 7;
  float s = 0.f;
  #pragma unroll
  for (int i = 0; i < C_ / 64; i++){
    int c = i * 64 + lane;
    s += Wp[(size_t)d * F_ + hh * C_ + c] * ap[hh * C_ + c];
  }
  s = waveSum(s);
  if (lane == 0) wvec[d * 16 + j] = s;
}

__global__ void build_wd2(const float* __restrict__ W2d, const float* __restrict__ a2d,
                          float* __restrict__ wd2){
  int k = blockIdx.x * blockDim.x + threadIdx.x;
  if (k < F_) wd2[k] = W2d[k * 2] * a2d[0] + W2d[k * 2 + 1] * a2d[1];
}

__global__ void init_buffers(unsigned* __restrict__ m1, float* __restrict__ den1,
                             unsigned* __restrict__ m2, float* __restrict__ den2,
                             int* __restrict__ cnt, float* __restrict__ s0a,
                             float* __restrict__ s1a, float* __restrict__ sda){
  int i = blockIdx.x * blockDim.x + threadIdx.x;
  if (i < N_ * H_){ m1[i] = ORD_NEG; den1[i] = 0.f; }
  if (i < N_){ m2[i] = ORD_NEG; den2[i] = 0.f; cnt[i] = 0;
               s0a[i] = 0.f; s1a[i] = 0.f; sda[i] = 0.f; }
}

// ---------- al_s1/al_d1 = x @ wvec ----------
__global__ __launch_bounds__(256) void al_build(const float* __restrict__ X,
                                                const float* __restrict__ wvec,
                                                float* __restrict__ al_s,
                                                float* __restrict__ al_d){
  int t = threadIdx.x;
  int n = blockIdx.x * 4 + (t >> 6);
  int lane = t & 63;
  float acc[16] = {};
  for (int i = 0; i < D_ / 64; i++){
    int d = i * 64 + lane;
    float xv = X[(size_t)n * D_ + d];
    const float4* wp = reinterpret_cast<const float4*>(wvec + d * 16);
    float4 w0 = wp[0], w1 = wp[1], w2 = wp[2], w3 = wp[3];
    acc[0] += xv*w0.x; acc[1] += xv*w0.y; acc[2]  += xv*w0.z; acc[3]  += xv*w0.w;
    acc[4] += xv*w1.x; acc[5] += xv*w1.y; acc[6]  += xv*w1.z; acc[7]  += xv*w1.w;
    acc[8] += xv*w2.x; acc[9] += xv*w2.y; acc[10] += xv*w2.z; acc[11] += xv*w2.w;
    acc[12]+= xv*w3.x; acc[13]+= xv*w3.y; acc[14] += xv*w3.z; acc[15] += xv*w3.w;
  }
  #pragma unroll
  for (int j = 0; j < 16; j++){
    float s = waveSum(acc[j]);
    if (lane == 0){
      if (j < 8) al_s[n * 8 + j] = s;
      else       al_d[n * 8 + (j - 8)] = s;
    }
  }
}

// ---------- layer-1 edge softmax ----------
__global__ void edge_max1(const int* __restrict__ ei, const float* __restrict__ al_s,
                          const float* __restrict__ al_d, unsigned* __restrict__ m1){
  int t = blockIdx.x * blockDim.x + threadIdx.x;
  if (t >= ET_ * H_) return;
  int e = t >> 3, hh = t & 7;
  int s = eSRC(ei, e), dd = eDST(ei, e);
  float lg = lrelu(al_s[s * 8 + hh] + al_d[dd * 8 + hh]);
  atomicMax(&m1[dd * 8 + hh], f2ord(lg));
}

__global__ void edge_exp1(const int* __restrict__ ei, const float* __restrict__ al_s,
                          const float* __restrict__ al_d, const unsigned* __restrict__ m1,
                          float* __restrict__ den1, float* __restrict__ expv){
  int t = blockIdx.x * blockDim.x + threadIdx.x;
  if (t >= ET_ * H_) return;
  int e = t >> 3, hh = t & 7;
  int s = eSRC(ei, e), dd = eDST(ei, e);
  float lg = lrelu(al_s[s * 8 + hh] + al_d[dd * 8 + hh]);
  float mv = ord2f(m1[dd * 8 + hh]);
  if (mv < -3.0e38f) mv = 0.f;
  float ev = expf(lg - mv);
  expv[e * 8 + hh] = ev;
  atomicAdd(&den1[dd * 8 + hh], ev);
}

// ---------- CSR build ----------
__global__ void edge_hist(const int* __restrict__ ei, int* __restrict__ cnt){
  int e = blockIdx.x * blockDim.x + threadIdx.x;
  if (e < ET_) atomicAdd(&cnt[eDST(ei, e)], 1);
}

__global__ __launch_bounds__(1024) void scan_kernel(const int* __restrict__ cnt,
                                                    int* __restrict__ off,
                                                    int* __restrict__ cur){
  __shared__ int sums[1024];
  int t = threadIdx.x;
  int base = t * 16;
  int loc[16]; int s = 0;
  #pragma unroll
  for (int i = 0; i < 16; i++){ loc[i] = s; s += cnt[base + i]; }
  sums[t] = s;
  __syncthreads();
  for (int o = 1; o < 1024; o <<= 1){
    int v = (t >= o) ? sums[t - o] : 0;
    __syncthreads();
    sums[t] += v;
    __syncthreads();
  }
  int prefix = sums[t] - s;
  #pragma unroll
  for (int i = 0; i < 16; i++){ off[base + i] = prefix + loc[i]; cur[base + i] = prefix + loc[i]; }
  if (t == 1023) off[N_] = prefix + s;
}

__global__ void edge_scatter(const int* __restrict__ ei, int* __restrict__ cur,
                             int* __restrict__ eid, int* __restrict__ srcs){
  int e = blockIdx.x * blockDim.x + threadIdx.x;
  if (e >= ET_) return;
  int dd = eDST(ei, e);
  int p = atomicAdd(&cur[dd], 1);
  eid[p] = e; srcs[p] = eSRC(ei, e);
}

// ---------- per-head bf16 MFMA GEMM: hsH = Xb @ Wt[colBase..colBase+512)^T ----------
// Xb: [N_][D_] bf16 row-major; Wt: [F_][D_] bf16 (W1s transposed).
// 128x128 tile, BK=64, 4 waves each owning 64x64, mfma_f32_16x16x32_bf16.
// LDS layout [row][kchunk] with content XOR-swizzled (kc ^= row&7) on BOTH the
// global-source side (pre-swizzle) and the ds_read side (rule #21).
__global__ __launch_bounds__(256) void gemm_mfma(const unsigned short* __restrict__ Xb,
                                                 const unsigned short* __restrict__ Wt,
                                                 unsigned short* __restrict__ outH,
                                                 int colBase){
  __shared__ unsigned short Al[128 * 64];
  __shared__ unsigned short Bl[128 * 64];
  int t = threadIdx.x;
  int bm = blockIdx.y * 128;
  int bn = blockIdx.x * 128;
  int w = t >> 6, l = t & 63;
  int lrow = l & 15, lk = l >> 4;
  int wr = w >> 1, wc = w & 1;
  f32x4 acc[4][4] = {};

  for (int k0 = 0; k0 < D_; k0 += 64){
    #pragma unroll
    for (int c = 0; c < 4; c++){
      int s = c * 256 + t;
      int row = s >> 3, kc = s & 7;
      int kcs = kc ^ (row & 7);
      int wbase = (c * 256 + (t & ~63)) * 8;   // ushort units, wave-uniform
      gl16(Xb + (size_t)(bm + row) * D_ + k0 + kcs * 8, &Al[wbase]);
      gl16(Wt + (size_t)(colBase + bn + row) * D_ + k0 + kcs * 8, &Bl[wbase]);
    }
    __syncthreads();   // drains vmcnt -> staged data visible
    #pragma unroll
    for (int kk = 0; kk < 2; kk++){
      int kc = kk * 4 + lk;
      bf16x8 af[4], bfr[4];
      #pragma unroll
      for (int f = 0; f < 4; f++){
        int row = wr * 64 + f * 16 + lrow;
        af[f]  = *reinterpret_cast<const bf16x8*>(&Al[row * 64 + ((kc ^ (row & 7)) << 3)]);
        int col = wc * 64 + f * 16 + lrow;
        bfr[f] = *reinterpret_cast<const bf16x8*>(&Bl[col * 64 + ((kc ^ (col & 7)) << 3)]);
      }
      #pragma unroll
      for (int mf = 0; mf < 4; mf++)
        #pragma unroll
        for (int nf = 0; nf < 4; nf++)
          acc[mf][nf] = __builtin_amdgcn_mfma_f32_16x16x32_bf16(af[mf], bfr[nf], acc[mf][nf], 0, 0, 0);
    }
    __syncthreads();   // all reads done before next stage overwrites
  }

  #pragma unroll
  for (int mf = 0; mf < 4; mf++)
    #pragma unroll
    for (int nf = 0; nf < 4; nf++)
      #pragma unroll
      for (int r = 0; r < 4; r++){
        int row = bm + wr * 64 + mf * 16 + lk * 4 + r;
        int col = bn + wc * 64 + nf * 16 + lrow;
        outH[(size_t)row * C_ + col] = f2bf(acc[mf][nf][r]);
      }
}

// ---------- per-head aggregation fused with layer-2 dot products ----------
__global__ __launch_bounds__(256) void agg_head(
    const unsigned short* __restrict__ hsH, const float* __restrict__ expv,
    const float* __restrict__ den1, const int* __restrict__ off,
    const int* __restrict__ eid, const int* __restrict__ srcs,
    const float* __restrict__ b1, const float* __restrict__ W2s,
    const float* __restrict__ wd2, int hh,
    float* __restrict__ s0a, float* __restrict__ s1a, float* __restrict__ sda){
  int t = threadIdx.x;
  int n = blockIdx.x * 4 + (t >> 6);
  int lane = t & 63;
  int c0 = lane * 8;                     // channel within head
  float inv = 1.f / (den1[n * 8 + hh] + 1e-16f);
  float acc[8] = {};
  int i0 = off[n], i1 = off[n + 1];
  for (int i = i0; i < i1; i++){
    int e = eid[i]; int s = srcs[i];
    float a = expv[e * 8 + hh] * inv;
    uint4 v = *reinterpret_cast<const uint4*>(hsH + (size_t)s * C_ + c0);
    acc[0] += a * bf2f_lo(v.x); acc[1] += a * bf2f_hi(v.x);
    acc[2] += a * bf2f_lo(v.y); acc[3] += a * bf2f_hi(v.y);
    acc[4] += a * bf2f_lo(v.z); acc[5] += a * bf2f_hi(v.z);
    acc[6] += a * bf2f_lo(v.w); acc[7] += a * bf2f_hi(v.w);
  }
  int gc = hh * C_ + c0;                 // global channel
  float4 bb0 = *reinterpret_cast<const float4*>(b1 + gc);
  float4 bb1 = *reinterpret_cast<const float4*>(b1 + gc + 4);
  acc[0] += bb0.x; acc[1] += bb0.y; acc[2] += bb0.z; acc[3] += bb0.w;
  acc[4] += bb1.x; acc[5] += bb1.y; acc[6] += bb1.z; acc[7] += bb1.w;
  float s0 = 0.f, s1 = 0.f, sd = 0.f;
  #pragma unroll
  for (int j = 0; j < 8; j++){
    float2 w = *reinterpret_cast<const float2*>(W2s + (size_t)(gc + j) * 2);
    s0 += acc[j] * w.x; s1 += acc[j] * w.y; sd += acc[j] * wd2[gc + j];
  }
  s0 = waveSum(s0); s1 = waveSum(s1); sd = waveSum(sd);
  if (lane == 0){
    s0a[n] += s0; s1a[n] += s1; sda[n] += sd;
  }
}

// ---------- layer-2 ----------
__global__ void finalize_l2(const float* __restrict__ s0a, const float* __restrict__ s1a,
                            const float* __restrict__ sda, const float* __restrict__ a2s,
                            float* __restrict__ als2, float* __restrict__ ald2){
  int n = blockIdx.x * blockDim.x + threadIdx.x;
  if (n >= N_) return;
  als2[n] = s0a[n] * a2s[0] + s1a[n] * a2s[1];
  ald2[n] = sda[n];
}

__global__ void edge_max2(const int* __restrict__ ei, const float* __restrict__ als2,
                          const float* __restrict__ ald2, unsigned* __restrict__ m2){
  int e = blockIdx.x * blockDim.x + threadIdx.x;
  if (e >= ET_) return;
  int dd = eDST(ei, e);
  float lg = lrelu(als2[eSRC(ei, e)] + ald2[dd]);
  atomicMax(&m2[dd], f2ord(lg));
}

__global__ void edge_exp2(const int* __restrict__ ei, const float* __restrict__ als2,
                          const float* __restrict__ ald2, const unsigned* __restrict__ m2,
                          float* __restrict__ den2, float* __restrict__ expv2){
  int e = blockIdx.x * blockDim.x + threadIdx.x;
  if (e >= ET_) return;
  int dd = eDST(ei, e);
  float lg = lrelu(als2[eSRC(ei, e)] + ald2[dd]);
  float mv = ord2f(m2[dd]);
  if (mv < -3.0e38f) mv = 0.f;
  float ev = expf(lg - mv);
  expv2[e] = ev;
  atomicAdd(&den2[dd], ev);
}

__global__ void aggregate2(const float* __restrict__ s0a, const float* __restrict__ s1a,
    const float* __restrict__ expv2, const float* __restrict__ den2,
    const int* __restrict__ off, const int* __restrict__ eid, const int* __restrict__ srcs,
    const float* __restrict__ b2, float* __restrict__ out){
  int n = blockIdx.x * blockDim.x + threadIdx.x;
  if (n >= N_) return;
  float inv = 1.f / (den2[n] + 1e-16f);
  float a0 = 0.f, a1 = 0.f;
  int i1 = off[n + 1];
  for (int i = off[n]; i < i1; i++){
    int e = eid[i], s = srcs[i];
    float a = expv2[e] * inv;
    a0 += a * s0a[s]; a1 += a * s1a[s];
  }
  out[2 * n]     = a0 + b2[0];
  out[2 * n + 1] = a1 + b2[1];
}

// ---------- host ----------
extern "C" void kernel_launch(void* const* d_in, const int* in_sizes, int n_in,
                              void* d_out, int out_size, void* d_ws, size_t ws_size,
                              hipStream_t stream){
  const float* x   = (const float*)d_in[0];
  const int*   ei  = (const int*)  d_in[1];
  const float* W1s = (const float*)d_in[2];
  const float* W1d = (const float*)d_in[3];
  const float* a1s = (const float*)d_in[4];
  const float* a1d = (const float*)d_in[5];
  const float* b1  = (const float*)d_in[6];
  const float* W2s = (const float*)d_in[7];
  const float* W2d = (const float*)d_in[8];
  const float* a2s = (const float*)d_in[9];
  const float* a2d = (const float*)d_in[10];
  const float* b2  = (const float*)d_in[11];
  float* out = (float*)d_out;

  char* p = (char*)d_ws;
  auto alloc = [&](size_t bytes) -> void* {
    void* r = (void*)p;
    p += (bytes + 255) & ~(size_t)255;
    return r;
  };
  unsigned short* hsH = (unsigned short*)alloc((size_t)N_ * C_ * 2);   // 16 MB
  unsigned short* Xb  = (unsigned short*)alloc((size_t)N_ * D_ * 2);   // 32 MB
  unsigned short* Wt  = (unsigned short*)alloc((size_t)F_ * D_ * 2);   // 8 MB
  float* al_s1 = (float*)alloc((size_t)N_ * H_ * 4);
  float* al_d1 = (float*)alloc((size_t)N_ * H_ * 4);
  float* wvec  = (float*)alloc((size_t)D_ * 16 * 4);
  unsigned* m1 = (unsigned*)alloc((size_t)N_ * H_ * 4);
  float* den1  = (float*)alloc((size_t)N_ * H_ * 4);
  float* expv1 = (float*)alloc((size_t)ET_ * H_ * 4);
  int* cnt  = (int*)alloc((size_t)N_ * 4);
  int* off  = (int*)alloc((size_t)(N_ + 1) * 4);
  int* cur  = (int*)alloc((size_t)N_ * 4);
  int* eid  = (int*)alloc((size_t)ET_ * 4);
  int* srcs = (int*)alloc((size_t)ET_ * 4);
  float* s0a = (float*)alloc((size_t)N_ * 4);
  float* s1a = (float*)alloc((size_t)N_ * 4);
  float* sda = (float*)alloc((size_t)N_ * 4);
  float* wd2 = (float*)alloc((size_t)F_ * 4);
  unsigned* m2 = (unsigned*)alloc((size_t)N_ * 4);
  float* den2  = (float*)alloc((size_t)N_ * 4);
  float* als2  = (float*)alloc((size_t)N_ * 4);
  float* ald2  = (float*)alloc((size_t)N_ * 4);
  float* expv2 = (float*)alloc((size_t)ET_ * 4);
  // total ≈ 63 MB

  // conversions + precompute
  x2bf<<<dim3(N_ * D_ / 8 / 256), dim3(256), 0, stream>>>(x, Xb);
  build_wt<<<dim3(F_ / 32, D_ / 32), dim3(1024), 0, stream>>>(W1s, Wt);
  build_wvec1<<<dim3(D_ * 16 / 4), dim3(256), 0, stream>>>(W1s, W1d, a1s, a1d, wvec);
  build_wd2<<<dim3(F_ / 256), dim3(256), 0, stream>>>(W2d, a2d, wd2);
  init_buffers<<<dim3(N_ * H_ / 256), dim3(256), 0, stream>>>(m1, den1, m2, den2, cnt,
                                                              s0a, s1a, sda);

  // layer-1 attention logits + softmax
  al_build<<<dim3(N_ / 4), dim3(256), 0, stream>>>(x, wvec, al_s1, al_d1);
  edge_max1<<<dim3(ET_ * H_ / 256), dim3(256), 0, stream>>>(ei, al_s1, al_d1, m1);
  edge_exp1<<<dim3(ET_ * H_ / 256), dim3(256), 0, stream>>>(ei, al_s1, al_d1, m1, den1, expv1);

  // CSR (shared by both layers)
  edge_hist<<<dim3(ET_ / 256), dim3(256), 0, stream>>>(ei, cnt);
  scan_kernel<<<dim3(1), dim3(1024), 0, stream>>>(cnt, off, cur);
  edge_scatter<<<dim3(ET_ / 256), dim3(256), 0, stream>>>(ei, cur, eid, srcs);

  // per-head: MFMA GEMM then fused aggregation + layer-2 partial dots
  for (int hh = 0; hh < H_; hh++){
    gemm_mfma<<<dim3(C_ / 128, N_ / 128), dim3(256), 0, stream>>>(Xb, Wt, hsH, hh * C_);
    agg_head<<<dim3(N_ / 4), dim3(256), 0, stream>>>(hsH, expv1, den1, off, eid, srcs,
                                                     b1, W2s, wd2, hh, s0a, s1a, sda);
  }

  // layer-2 softmax + aggregation
  finalize_l2<<<dim3(N_ / 256), dim3(256), 0, stream>>>(s0a, s1a, sda, a2s, als2, ald2);
  edge_max2<<<dim3(ET_ / 256), dim3(256), 0, stream>>>(ei, als2, ald2, m2);
  edge_exp2<<<dim3(ET_ / 256), dim3(256), 0, stream>>>(ei, als2, ald2, m2, den2, expv2);
  aggregate2<<<dim3(N_ / 256), dim3(256), 0, stream>>>(s0a, s1a, expv2, den2,
                                                       off, eid, srcs, b2, out);
}

// Round 4
// 353.809 us; speedup vs baseline: 6.7544x; 1.4627x over previous
//
#include <hip/hip_runtime.h>
#include <cstdint>
#include <cstddef>

#define DEV __device__ __forceinline__

typedef __attribute__((ext_vector_type(8))) short bf16x8;
typedef __attribute__((ext_vector_type(4))) float f32x4;

constexpr int N_  = 16384;
constexpr int D_  = 1024;
constexpr int E_  = 65536;
constexpr int ET_ = E_ + N_;   // 81920 edges incl. self loops
constexpr int H_  = 8;
constexpr int C_  = 512;
constexpr int F_  = 4096;      // H_*C_
constexpr unsigned ORD_NEG = 0x007FFFFFu; // f2ord(-inf)

// ---------- helpers ----------
DEV unsigned short f2bf(float f){
  unsigned u = __float_as_uint(f);
  unsigned r = u + 0x7FFFu + ((u >> 16) & 1u); // RNE
  return (unsigned short)(r >> 16);
}
DEV float bf2f_lo(unsigned u){ return __uint_as_float(u << 16); }
DEV float bf2f_hi(unsigned u){ return __uint_as_float(u & 0xFFFF0000u); }
DEV unsigned pack2bf(float lo, float hi){
  return (unsigned)f2bf(lo) | ((unsigned)f2bf(hi) << 16);
}
DEV unsigned f2ord(float f){
  unsigned u = __float_as_uint(f);
  return (u & 0x80000000u) ? ~u : (u | 0x80000000u);
}
DEV float ord2f(unsigned u){
  return (u & 0x80000000u) ? __uint_as_float(u ^ 0x80000000u) : __uint_as_float(~u);
}
DEV float lrelu(float x){ return x >= 0.f ? x : 0.2f * x; }
DEV float waveSum(float v){
  #pragma unroll
  for (int o = 32; o > 0; o >>= 1) v += __shfl_xor(v, o);
  return v;
}
DEV int eSRC(const int* ei, int e){ return e < E_ ? ei[e]      : e - E_; }
DEV int eDST(const int* ei, int e){ return e < E_ ? ei[E_ + e] : e - E_; }

DEV void gl16(const unsigned short* g, unsigned short* l){
  __builtin_amdgcn_global_load_lds(
      (const __attribute__((address_space(1))) void*)g,
      (__attribute__((address_space(3))) void*)l, 16, 0, 0);
}

// ---------- dtype conversions ----------
__global__ void x2bf(const float* __restrict__ X, unsigned short* __restrict__ Xb){
  int i = (blockIdx.x * blockDim.x + threadIdx.x) * 8;
  float4 v0 = *reinterpret_cast<const float4*>(X + i);
  float4 v1 = *reinterpret_cast<const float4*>(X + i + 4);
  uint4 o;
  o.x = pack2bf(v0.x, v0.y); o.y = pack2bf(v0.z, v0.w);
  o.z = pack2bf(v1.x, v1.y); o.w = pack2bf(v1.z, v1.w);
  *reinterpret_cast<uint4*>(Xb + i) = o;
}

// Wt[f][k] = bf16(W1s[k][f])
__global__ __launch_bounds__(1024) void build_wt(const float* __restrict__ W,
                                                 unsigned short* __restrict__ Wt){
  __shared__ float tile[32][33];
  int f0 = blockIdx.x * 32, k0 = blockIdx.y * 32;
  int tx = threadIdx.x & 31, ty = threadIdx.x >> 5;
  tile[ty][tx] = W[(size_t)(k0 + ty) * F_ + f0 + tx];
  __syncthreads();
  Wt[(size_t)(f0 + ty) * D_ + k0 + tx] = f2bf(tile[tx][ty]);
}

// ---------- precompute: wvecBf = MFMA-B-fragment-ordered bf16 of wvec ----------
// wvec[d][j] (j<8: W1s-block-h . a1s[h]; j>=8: W1d . a1d), stored so that
// lane l of a 16x16x32 MFMA reads its B-frag contiguously:
// wvecBf[((d>>5)*64 + ((d>>3)&3)*16 + j)*8 + (d&7)]
__global__ __launch_bounds__(256) void build_wvec1(
    const float* __restrict__ W1s, const float* __restrict__ W1d,
    const float* __restrict__ a1s, const float* __restrict__ a1d,
    unsigned short* __restrict__ wvecBf){
  int t = threadIdx.x;
  int id = blockIdx.x * 4 + (t >> 6);
  int lane = t & 63;
  int d = id >> 4, j = id & 15;
  const float* Wp = (j < 8) ? W1s : W1d;
  const float* ap = (j < 8) ? a1s : a1d;
  int hh = j & 7;
  float s = 0.f;
  #pragma unroll
  for (int i = 0; i < C_ / 64; i++){
    int c = i * 64 + lane;
    s += Wp[(size_t)d * F_ + hh * C_ + c] * ap[hh * C_ + c];
  }
  s = waveSum(s);
  if (lane == 0){
    int idx = ((d >> 5) * 64 + ((d >> 3) & 3) * 16 + j) * 8 + (d & 7);
    wvecBf[idx] = f2bf(s);
  }
}

__global__ void build_wd2(const float* __restrict__ W2d, const float* __restrict__ a2d,
                          float* __restrict__ wd2){
  int k = blockIdx.x * blockDim.x + threadIdx.x;
  if (k < F_) wd2[k] = W2d[k * 2] * a2d[0] + W2d[k * 2 + 1] * a2d[1];
}

__global__ void init_buffers(unsigned* __restrict__ m1, float* __restrict__ den1,
                             unsigned* __restrict__ m2, float* __restrict__ den2,
                             int* __restrict__ cnt, float* __restrict__ s0a,
                             float* __restrict__ s1a, float* __restrict__ sda){
  int i = blockIdx.x * blockDim.x + threadIdx.x;
  if (i < N_ * H_){ m1[i] = ORD_NEG; den1[i] = 0.f; }
  if (i < N_){ m2[i] = ORD_NEG; den2[i] = 0.f; cnt[i] = 0;
               s0a[i] = 0.f; s1a[i] = 0.f; sda[i] = 0.f; }
}

// ---------- al via MFMA: [N,1024]bf16 @ [1024,16]bf16 -> al_s/al_d ----------
__global__ __launch_bounds__(256) void al_mfma(const unsigned short* __restrict__ Xb,
                                               const unsigned short* __restrict__ wvecBf,
                                               float* __restrict__ al_s,
                                               float* __restrict__ al_d){
  int t = threadIdx.x;
  int wid = t >> 6, lane = t & 63;
  int n0 = (blockIdx.x * 4 + wid) * 16;
  int row = lane & 15, ks = lane >> 4;
  f32x4 acc = {0.f, 0.f, 0.f, 0.f};
  #pragma unroll
  for (int kc = 0; kc < D_ / 32; kc++){
    bf16x8 a = *reinterpret_cast<const bf16x8*>(&Xb[(size_t)(n0 + row) * D_ + kc * 32 + ks * 8]);
    bf16x8 b = *reinterpret_cast<const bf16x8*>(&wvecBf[(kc * 64 + lane) * 8]);
    acc = __builtin_amdgcn_mfma_f32_16x16x32_bf16(a, b, acc, 0, 0, 0);
  }
  int j = lane & 15;
  #pragma unroll
  for (int r = 0; r < 4; r++){
    int n = n0 + ks * 4 + r;
    float v = acc[r];
    if (j < 8) al_s[n * 8 + j] = v;
    else       al_d[n * 8 + (j - 8)] = v;
  }
}

// ---------- layer-1 edge softmax ----------
__global__ void edge_max1(const int* __restrict__ ei, const float* __restrict__ al_s,
                          const float* __restrict__ al_d, unsigned* __restrict__ m1){
  int t = blockIdx.x * blockDim.x + threadIdx.x;
  if (t >= ET_ * H_) return;
  int e = t >> 3, hh = t & 7;
  int s = eSRC(ei, e), dd = eDST(ei, e);
  float lg = lrelu(al_s[s * 8 + hh] + al_d[dd * 8 + hh]);
  atomicMax(&m1[dd * 8 + hh], f2ord(lg));
}

__global__ void edge_exp1(const int* __restrict__ ei, const float* __restrict__ al_s,
                          const float* __restrict__ al_d, const unsigned* __restrict__ m1,
                          float* __restrict__ den1, float* __restrict__ expv){
  int t = blockIdx.x * blockDim.x + threadIdx.x;
  if (t >= ET_ * H_) return;
  int e = t >> 3, hh = t & 7;
  int s = eSRC(ei, e), dd = eDST(ei, e);
  float lg = lrelu(al_s[s * 8 + hh] + al_d[dd * 8 + hh]);
  float mv = ord2f(m1[dd * 8 + hh]);
  if (mv < -3.0e38f) mv = 0.f;
  float ev = expf(lg - mv);
  expv[e * 8 + hh] = ev;
  atomicAdd(&den1[dd * 8 + hh], ev);
}

// ---------- CSR build ----------
__global__ void edge_hist(const int* __restrict__ ei, int* __restrict__ cnt){
  int e = blockIdx.x * blockDim.x + threadIdx.x;
  if (e < ET_) atomicAdd(&cnt[eDST(ei, e)], 1);
}

__global__ __launch_bounds__(1024) void scan_kernel(const int* __restrict__ cnt,
                                                    int* __restrict__ off,
                                                    int* __restrict__ cur){
  __shared__ int sums[1024];
  int t = threadIdx.x;
  int base = t * 16;
  int loc[16]; int s = 0;
  #pragma unroll
  for (int i = 0; i < 16; i++){ loc[i] = s; s += cnt[base + i]; }
  sums[t] = s;
  __syncthreads();
  for (int o = 1; o < 1024; o <<= 1){
    int v = (t >= o) ? sums[t - o] : 0;
    __syncthreads();
    sums[t] += v;
    __syncthreads();
  }
  int prefix = sums[t] - s;
  #pragma unroll
  for (int i = 0; i < 16; i++){ off[base + i] = prefix + loc[i]; cur[base + i] = prefix + loc[i]; }
  if (t == 1023) off[N_] = prefix + s;
}

__global__ void edge_scatter(const int* __restrict__ ei, int* __restrict__ cur,
                             int* __restrict__ eid, int* __restrict__ srcs){
  int e = blockIdx.x * blockDim.x + threadIdx.x;
  if (e >= ET_) return;
  int dd = eDST(ei, e);
  int p = atomicAdd(&cur[dd], 1);
  eid[p] = e; srcs[p] = eSRC(ei, e);
}

// ---------- bf16 MFMA GEMM: out = Xb @ Wt[colBase..]^T, leading dim ld ----------
// 128x128 tile, BK=64, 4 waves each owning 64x64, mfma_f32_16x16x32_bf16.
// XOR-swizzle applied on BOTH the global-source side and the ds_read side.
__global__ __launch_bounds__(256) void gemm_mfma(const unsigned short* __restrict__ Xb,
                                                 const unsigned short* __restrict__ Wt,
                                                 unsigned short* __restrict__ outH,
                                                 int colBase, int ld){
  __shared__ unsigned short Al[128 * 64];
  __shared__ unsigned short Bl[128 * 64];
  int t = threadIdx.x;
  int bm = blockIdx.y * 128;
  int bn = blockIdx.x * 128;
  int w = t >> 6, l = t & 63;
  int lrow = l & 15, lk = l >> 4;
  int wr = w >> 1, wc = w & 1;
  f32x4 acc[4][4] = {};

  for (int k0 = 0; k0 < D_; k0 += 64){
    #pragma unroll
    for (int c = 0; c < 4; c++){
      int s = c * 256 + t;
      int row = s >> 3, kc = s & 7;
      int kcs = kc ^ (row & 7);
      int wbase = (c * 256 + (t & ~63)) * 8;   // ushort units, wave-uniform
      gl16(Xb + (size_t)(bm + row) * D_ + k0 + kcs * 8, &Al[wbase]);
      gl16(Wt + (size_t)(colBase + bn + row) * D_ + k0 + kcs * 8, &Bl[wbase]);
    }
    __syncthreads();
    #pragma unroll
    for (int kk = 0; kk < 2; kk++){
      int kc = kk * 4 + lk;
      bf16x8 af[4], bfr[4];
      #pragma unroll
      for (int f = 0; f < 4; f++){
        int row = wr * 64 + f * 16 + lrow;
        af[f]  = *reinterpret_cast<const bf16x8*>(&Al[row * 64 + ((kc ^ (row & 7)) << 3)]);
        int col = wc * 64 + f * 16 + lrow;
        bfr[f] = *reinterpret_cast<const bf16x8*>(&Bl[col * 64 + ((kc ^ (col & 7)) << 3)]);
      }
      #pragma unroll
      for (int mf = 0; mf < 4; mf++)
        #pragma unroll
        for (int nf = 0; nf < 4; nf++)
          acc[mf][nf] = __builtin_amdgcn_mfma_f32_16x16x32_bf16(af[mf], bfr[nf], acc[mf][nf], 0, 0, 0);
    }
    __syncthreads();
  }

  #pragma unroll
  for (int mf = 0; mf < 4; mf++)
    #pragma unroll
    for (int nf = 0; nf < 4; nf++)
      #pragma unroll
      for (int r = 0; r < 4; r++){
        int row = bm + wr * 64 + mf * 16 + lk * 4 + r;
        int col = bn + wc * 64 + nf * 16 + lrow;
        outH[(size_t)row * ld + col] = f2bf(acc[mf][nf][r]);
      }
}

// ---------- combined aggregation over all heads, fused layer-2 dots ----------
// one block per node, 8 waves = 8 heads; exclusive writer -> no atomics
__global__ __launch_bounds__(512) void agg_all(
    const unsigned short* __restrict__ hsA, const float* __restrict__ expv,
    const float* __restrict__ den1, const int* __restrict__ off,
    const int* __restrict__ eid, const int* __restrict__ srcs,
    const float* __restrict__ b1, const float* __restrict__ W2s,
    const float* __restrict__ wd2, const float* __restrict__ a2s,
    float* __restrict__ s0a, float* __restrict__ s1a, float* __restrict__ sda,
    float* __restrict__ als2, float* __restrict__ ald2){
  __shared__ float red[3][8];
  int n = blockIdx.x;
  int t = threadIdx.x;
  int w = t >> 6, lane = t & 63;
  int gc = w * C_ + lane * 8;
  float inv = 1.f / (den1[n * 8 + w] + 1e-16f);
  float acc[8] = {};
  int i0 = off[n], i1 = off[n + 1];
  for (int i = i0; i < i1; i++){
    int e = eid[i]; int s = srcs[i];
    float a = expv[e * 8 + w] * inv;
    uint4 v = *reinterpret_cast<const uint4*>(hsA + (size_t)s * F_ + gc);
    acc[0] += a * bf2f_lo(v.x); acc[1] += a * bf2f_hi(v.x);
    acc[2] += a * bf2f_lo(v.y); acc[3] += a * bf2f_hi(v.y);
    acc[4] += a * bf2f_lo(v.z); acc[5] += a * bf2f_hi(v.z);
    acc[6] += a * bf2f_lo(v.w); acc[7] += a * bf2f_hi(v.w);
  }
  float4 bb0 = *reinterpret_cast<const float4*>(b1 + gc);
  float4 bb1 = *reinterpret_cast<const float4*>(b1 + gc + 4);
  acc[0] += bb0.x; acc[1] += bb0.y; acc[2] += bb0.z; acc[3] += bb0.w;
  acc[4] += bb1.x; acc[5] += bb1.y; acc[6] += bb1.z; acc[7] += bb1.w;
  float s0 = 0.f, s1 = 0.f, sd = 0.f;
  #pragma unroll
  for (int j = 0; j < 8; j++){
    float2 wv = *reinterpret_cast<const float2*>(W2s + (size_t)(gc + j) * 2);
    s0 += acc[j] * wv.x; s1 += acc[j] * wv.y; sd += acc[j] * wd2[gc + j];
  }
  s0 = waveSum(s0); s1 = waveSum(s1); sd = waveSum(sd);
  if (lane == 0){ red[0][w] = s0; red[1][w] = s1; red[2][w] = sd; }
  __syncthreads();
  if (t == 0){
    float t0 = 0.f, t1 = 0.f, t2 = 0.f;
    #pragma unroll
    for (int j = 0; j < 8; j++){ t0 += red[0][j]; t1 += red[1][j]; t2 += red[2][j]; }
    s0a[n] = t0; s1a[n] = t1; sda[n] = t2;
    als2[n] = t0 * a2s[0] + t1 * a2s[1];
    ald2[n] = t2;
  }
}

// ---------- per-head aggregation (fallback path) ----------
__global__ __launch_bounds__(256) void agg_head(
    const unsigned short* __restrict__ hsH, const float* __restrict__ expv,
    const float* __restrict__ den1, const int* __restrict__ off,
    const int* __restrict__ eid, const int* __restrict__ srcs,
    const float* __restrict__ b1, const float* __restrict__ W2s,
    const float* __restrict__ wd2, int hh,
    float* __restrict__ s0a, float* __restrict__ s1a, float* __restrict__ sda){
  int t = threadIdx.x;
  int n = blockIdx.x * 4 + (t >> 6);
  int lane = t & 63;
  int c0 = lane * 8;
  float inv = 1.f / (den1[n * 8 + hh] + 1e-16f);
  float acc[8] = {};
  int i0 = off[n], i1 = off[n + 1];
  for (int i = i0; i < i1; i++){
    int e = eid[i]; int s = srcs[i];
    float a = expv[e * 8 + hh] * inv;
    uint4 v = *reinterpret_cast<const uint4*>(hsH + (size_t)s * C_ + c0);
    acc[0] += a * bf2f_lo(v.x); acc[1] += a * bf2f_hi(v.x);
    acc[2] += a * bf2f_lo(v.y); acc[3] += a * bf2f_hi(v.y);
    acc[4] += a * bf2f_lo(v.z); acc[5] += a * bf2f_hi(v.z);
    acc[6] += a * bf2f_lo(v.w); acc[7] += a * bf2f_hi(v.w);
  }
  int gc = hh * C_ + c0;
  float4 bb0 = *reinterpret_cast<const float4*>(b1 + gc);
  float4 bb1 = *reinterpret_cast<const float4*>(b1 + gc + 4);
  acc[0] += bb0.x; acc[1] += bb0.y; acc[2] += bb0.z; acc[3] += bb0.w;
  acc[4] += bb1.x; acc[5] += bb1.y; acc[6] += bb1.z; acc[7] += bb1.w;
  float s0 = 0.f, s1 = 0.f, sd = 0.f;
  #pragma unroll
  for (int j = 0; j < 8; j++){
    float2 w = *reinterpret_cast<const float2*>(W2s + (size_t)(gc + j) * 2);
    s0 += acc[j] * w.x; s1 += acc[j] * w.y; sd += acc[j] * wd2[gc + j];
  }
  s0 = waveSum(s0); s1 = waveSum(s1); sd = waveSum(sd);
  if (lane == 0){
    s0a[n] += s0; s1a[n] += s1; sda[n] += sd;
  }
}

// ---------- layer-2 ----------
__global__ void finalize_l2(const float* __restrict__ s0a, const float* __restrict__ s1a,
                            const float* __restrict__ sda, const float* __restrict__ a2s,
                            float* __restrict__ als2, float* __restrict__ ald2){
  int n = blockIdx.x * blockDim.x + threadIdx.x;
  if (n >= N_) return;
  als2[n] = s0a[n] * a2s[0] + s1a[n] * a2s[1];
  ald2[n] = sda[n];
}

__global__ void edge_max2(const int* __restrict__ ei, const float* __restrict__ als2,
                          const float* __restrict__ ald2, unsigned* __restrict__ m2){
  int e = blockIdx.x * blockDim.x + threadIdx.x;
  if (e >= ET_) return;
  int dd = eDST(ei, e);
  float lg = lrelu(als2[eSRC(ei, e)] + ald2[dd]);
  atomicMax(&m2[dd], f2ord(lg));
}

__global__ void edge_exp2(const int* __restrict__ ei, const float* __restrict__ als2,
                          const float* __restrict__ ald2, const unsigned* __restrict__ m2,
                          float* __restrict__ den2, float* __restrict__ expv2){
  int e = blockIdx.x * blockDim.x + threadIdx.x;
  if (e >= ET_) return;
  int dd = eDST(ei, e);
  float lg = lrelu(als2[eSRC(ei, e)] + ald2[dd]);
  float mv = ord2f(m2[dd]);
  if (mv < -3.0e38f) mv = 0.f;
  float ev = expf(lg - mv);
  expv2[e] = ev;
  atomicAdd(&den2[dd], ev);
}

__global__ void aggregate2(const float* __restrict__ s0a, const float* __restrict__ s1a,
    const float* __restrict__ expv2, const float* __restrict__ den2,
    const int* __restrict__ off, const int* __restrict__ eid, const int* __restrict__ srcs,
    const float* __restrict__ b2, float* __restrict__ out){
  int n = blockIdx.x * blockDim.x + threadIdx.x;
  if (n >= N_) return;
  float inv = 1.f / (den2[n] + 1e-16f);
  float a0 = 0.f, a1 = 0.f;
  int i1 = off[n + 1];
  for (int i = off[n]; i < i1; i++){
    int e = eid[i], s = srcs[i];
    float a = expv2[e] * inv;
    a0 += a * s0a[s]; a1 += a * s1a[s];
  }
  out[2 * n]     = a0 + b2[0];
  out[2 * n + 1] = a1 + b2[1];
}

// ---------- host ----------
extern "C" void kernel_launch(void* const* d_in, const int* in_sizes, int n_in,
                              void* d_out, int out_size, void* d_ws, size_t ws_size,
                              hipStream_t stream){
  const float* x   = (const float*)d_in[0];
  const int*   ei  = (const int*)  d_in[1];
  const float* W1s = (const float*)d_in[2];
  const float* W1d = (const float*)d_in[3];
  const float* a1s = (const float*)d_in[4];
  const float* a1d = (const float*)d_in[5];
  const float* b1  = (const float*)d_in[6];
  const float* W2s = (const float*)d_in[7];
  const float* W2d = (const float*)d_in[8];
  const float* a2s = (const float*)d_in[9];
  const float* a2d = (const float*)d_in[10];
  const float* b2  = (const float*)d_in[11];
  float* out = (float*)d_out;

  // combined path needs ~175 MB of workspace; fall back to per-head otherwise
  const bool big = ws_size >= (size_t)185 * 1024 * 1024;

  char* p = (char*)d_ws;
  auto alloc = [&](size_t bytes) -> void* {
    void* r = (void*)p;
    p += (bytes + 255) & ~(size_t)255;
    return r;
  };
  unsigned short* hs  = (unsigned short*)alloc(big ? (size_t)N_ * F_ * 2
                                                   : (size_t)N_ * C_ * 2);
  unsigned short* Xb  = (unsigned short*)alloc((size_t)N_ * D_ * 2);   // 32 MB
  unsigned short* Wt  = (unsigned short*)alloc((size_t)F_ * D_ * 2);   // 8 MB
  unsigned short* wvecBf = (unsigned short*)alloc((size_t)D_ * 16 * 2);
  float* al_s1 = (float*)alloc((size_t)N_ * H_ * 4);
  float* al_d1 = (float*)alloc((size_t)N_ * H_ * 4);
  unsigned* m1 = (unsigned*)alloc((size_t)N_ * H_ * 4);
  float* den1  = (float*)alloc((size_t)N_ * H_ * 4);
  float* expv1 = (float*)alloc((size_t)ET_ * H_ * 4);
  int* cnt  = (int*)alloc((size_t)N_ * 4);
  int* off  = (int*)alloc((size_t)(N_ + 1) * 4);
  int* cur  = (int*)alloc((size_t)N_ * 4);
  int* eid  = (int*)alloc((size_t)ET_ * 4);
  int* srcs = (int*)alloc((size_t)ET_ * 4);
  float* s0a = (float*)alloc((size_t)N_ * 4);
  float* s1a = (float*)alloc((size_t)N_ * 4);
  float* sda = (float*)alloc((size_t)N_ * 4);
  float* wd2 = (float*)alloc((size_t)F_ * 4);
  unsigned* m2 = (unsigned*)alloc((size_t)N_ * 4);
  float* den2  = (float*)alloc((size_t)N_ * 4);
  float* als2  = (float*)alloc((size_t)N_ * 4);
  float* ald2  = (float*)alloc((size_t)N_ * 4);
  float* expv2 = (float*)alloc((size_t)ET_ * 4);

  // conversions + precompute
  x2bf<<<dim3(N_ * D_ / 8 / 256), dim3(256), 0, stream>>>(x, Xb);
  build_wt<<<dim3(F_ / 32, D_ / 32), dim3(1024), 0, stream>>>(W1s, Wt);
  build_wvec1<<<dim3(D_ * 16 / 4), dim3(256), 0, stream>>>(W1s, W1d, a1s, a1d, wvecBf);
  build_wd2<<<dim3(F_ / 256), dim3(256), 0, stream>>>(W2d, a2d, wd2);
  init_buffers<<<dim3(N_ * H_ / 256), dim3(256), 0, stream>>>(m1, den1, m2, den2, cnt,
                                                              s0a, s1a, sda);

  // layer-1 attention logits (MFMA) + softmax
  al_mfma<<<dim3(N_ / 64), dim3(256), 0, stream>>>(Xb, wvecBf, al_s1, al_d1);
  edge_max1<<<dim3(ET_ * H_ / 256), dim3(256), 0, stream>>>(ei, al_s1, al_d1, m1);
  edge_exp1<<<dim3(ET_ * H_ / 256), dim3(256), 0, stream>>>(ei, al_s1, al_d1, m1, den1, expv1);

  // CSR (shared by both layers)
  edge_hist<<<dim3(ET_ / 256), dim3(256), 0, stream>>>(ei, cnt);
  scan_kernel<<<dim3(1), dim3(1024), 0, stream>>>(cnt, off, cur);
  edge_scatter<<<dim3(ET_ / 256), dim3(256), 0, stream>>>(ei, cur, eid, srcs);

  if (big){
    // one GEMM over all heads, one aggregation pass (layer-2 logits fused)
    gemm_mfma<<<dim3(F_ / 128, N_ / 128), dim3(256), 0, stream>>>(Xb, Wt, hs, 0, F_);
    agg_all<<<dim3(N_), dim3(512), 0, stream>>>(hs, expv1, den1, off, eid, srcs,
                                                b1, W2s, wd2, a2s,
                                                s0a, s1a, sda, als2, ald2);
  } else {
    for (int hh = 0; hh < H_; hh++){
      gemm_mfma<<<dim3(C_ / 128, N_ / 128), dim3(256), 0, stream>>>(Xb, Wt, hs, hh * C_, C_);
      agg_head<<<dim3(N_ / 4), dim3(256), 0, stream>>>(hs, expv1, den1, off, eid, srcs,
                                                       b1, W2s, wd2, hh, s0a, s1a, sda);
    }
    finalize_l2<<<dim3(N_ / 256), dim3(256), 0, stream>>>(s0a, s1a, sda, a2s, als2, ald2);
  }

  // layer-2 softmax + aggregation
  edge_max2<<<dim3(ET_ / 256), dim3(256), 0, stream>>>(ei, als2, ald2, m2);
  edge_exp2<<<dim3(ET_ / 256), dim3(256), 0, stream>>>(ei, als2, ald2, m2, den2, expv2);
  aggregate2<<<dim3(N_ / 256), dim3(256), 0, stream>>>(s0a, s1a, expv2, den2,
                                                       off, eid, srcs, b2, out);
}

// Round 5
// 80.853 us; speedup vs baseline: 29.5568x; 4.3759x over previous
//
#include <hip/hip_runtime.h>
#include <cstdint>
#include <cstddef>

#define DEV __device__ __forceinline__

typedef __attribute__((ext_vector_type(8))) short bf16x8;
typedef __attribute__((ext_vector_type(4))) float f32x4;

constexpr int N_  = 16384;
constexpr int D_  = 1024;
constexpr int E_  = 65536;
constexpr int ET_ = E_ + N_;   // edges incl. self loops
constexpr int H_  = 8;
constexpr int C_  = 512;
constexpr int F_  = 4096;      // H_*C_
constexpr int ZS_ = 48;        // per-node scalar block: [al_s 0..7 | al_d 8..15 |
                               //  z0 16..23 | z1 24..31 | zd 32..39 | pad 40..47]

// ---------- helpers ----------
DEV unsigned short f2bf(float f){
  unsigned u = __float_as_uint(f);
  unsigned r = u + 0x7FFFu + ((u >> 16) & 1u); // RNE
  return (unsigned short)(r >> 16);
}
DEV float lrelu(float x){ return x >= 0.f ? x : 0.2f * x; }
DEV float waveSum(float v){
  #pragma unroll
  for (int o = 32; o > 0; o >>= 1) v += __shfl_xor(v, o);
  return v;
}
DEV int eSRC(const int* ei, int e){ return e < E_ ? ei[e]      : e - E_; }
DEV int eDST(const int* ei, int e){ return e < E_ ? ei[E_ + e] : e - E_; }

// ---------- init: zero accumulators + Vb pad ----------
__global__ void init_all(float* __restrict__ den1, float* __restrict__ den2,
                         float* __restrict__ s0a, float* __restrict__ s1a,
                         float* __restrict__ sda, unsigned* __restrict__ vbz){
  int i = blockIdx.x * blockDim.x + threadIdx.x;
  if (i < N_ * H_) den1[i] = 0.f;
  if (i < N_){ den2[i] = 0.f; s0a[i] = 0.f; s1a[i] = 0.f; sda[i] = 0.f; }
  if (i < 3 * 32 * 64 * 8 / 2) vbz[i] = 0u;   // 96 KB Vb zeroed (pad cols stay 0)
}

// ---------- wd2[k] = W2d[k,0]*a2d[0] + W2d[k,1]*a2d[1] ----------
__global__ void build_wd2(const float* __restrict__ W2d, const float* __restrict__ a2d,
                          float* __restrict__ wd2){
  int k = blockIdx.x * blockDim.x + threadIdx.x;
  if (k < F_) wd2[k] = W2d[k * 2] * a2d[0] + W2d[k * 2 + 1] * a2d[1];
}

// ---------- cb = (b1.W2s[:,0], b1.W2s[:,1], b1.wd2) ----------
__global__ __launch_bounds__(256) void build_cb(const float* __restrict__ b1,
                                                const float* __restrict__ W2s,
                                                const float* __restrict__ wd2,
                                                float* __restrict__ cb){
  __shared__ float red[3][4];
  int t = threadIdx.x, w = t >> 6, lane = t & 63;
  float p0 = 0.f, p1 = 0.f, pd = 0.f;
  for (int k = t; k < F_; k += 256){
    float b = b1[k];
    p0 += b * W2s[k * 2]; p1 += b * W2s[k * 2 + 1]; pd += b * wd2[k];
  }
  p0 = waveSum(p0); p1 = waveSum(p1); pd = waveSum(pd);
  if (lane == 0){ red[0][w] = p0; red[1][w] = p1; red[2][w] = pd; }
  __syncthreads();
  if (t == 0){
    cb[0] = red[0][0] + red[0][1] + red[0][2] + red[0][3];
    cb[1] = red[1][0] + red[1][1] + red[1][2] + red[1][3];
    cb[2] = red[2][0] + red[2][1] + red[2][2] + red[2][3];
  }
}

// ---------- build combined projection matrix Vb [1024 x 48] (MFMA-B-frag bf16) ----------
// col jj of V:  jj=h: W1s-block-h . a1s[h]      (al_src)
//               jj=8+h: W1d-block-h . a1d[h]    (al_dst)
//               jj=16+h: W1s-block-h . W2s[:,0] (z0)
//               jj=24+h: W1s-block-h . W2s[:,1] (z1)
//               jj=32+h: W1s-block-h . wd2      (zd)
// frag order (verified on-HW in prior rounds): value V[d][jj] at
//   Vb[((tt*32+kc)*64 + ks*16 + j)*8 + i], tt=jj>>4, j=jj&15, kc=d>>5, ks=(d>>3)&3, i=d&7
__global__ __launch_bounds__(256) void build_V(
    const float* __restrict__ W1s, const float* __restrict__ W1d,
    const float* __restrict__ a1s, const float* __restrict__ a1d,
    const float* __restrict__ W2s, const float* __restrict__ wd2,
    unsigned short* __restrict__ Vb){
  int t = threadIdx.x;
  int id = blockIdx.x * 4 + (t >> 6);      // 0..8191
  int lane = t & 63;
  int d = id >> 3, h = id & 7;
  float sa = 0.f, sb = 0.f, s0 = 0.f, s1 = 0.f, sd = 0.f;
  #pragma unroll
  for (int i = 0; i < C_ / 64; i++){
    int c = i * 64 + lane;
    int gc = h * C_ + c;
    float ws = W1s[(size_t)d * F_ + gc];
    float wdv = W1d[(size_t)d * F_ + gc];
    sa += ws * a1s[gc]; sb += wdv * a1d[gc];
    float2 w2 = *reinterpret_cast<const float2*>(W2s + (size_t)gc * 2);
    s0 += ws * w2.x; s1 += ws * w2.y; sd += ws * wd2[gc];
  }
  sa = waveSum(sa); sb = waveSum(sb);
  s0 = waveSum(s0); s1 = waveSum(s1); sd = waveSum(sd);
  if (lane == 0){
    int kc = d >> 5, ks = (d >> 3) & 3, ii = d & 7;
    auto put = [&](int jj, float v){
      int tt = jj >> 4, j = jj & 15;
      Vb[((size_t)(tt * 32 + kc) * 64 + ks * 16 + j) * 8 + ii] = f2bf(v);
    };
    put(h, sa); put(8 + h, sb); put(16 + h, s0); put(24 + h, s1); put(32 + h, sd);
  }
}

// ---------- node transform: Z[n][0..47] = x[n] @ V  (one MFMA wave per 16 nodes) ----------
__global__ __launch_bounds__(64) void node_mfma(const float* __restrict__ X,
                                                const unsigned short* __restrict__ Vb,
                                                float* __restrict__ Z){
  int lane = threadIdx.x;
  int n0 = blockIdx.x * 16;
  int row = lane & 15, ks = lane >> 4;
  f32x4 ac0 = {0.f,0.f,0.f,0.f}, ac1 = ac0, ac2 = ac0;
  const float* xp = X + (size_t)(n0 + row) * D_ + ks * 8;
  #pragma unroll 2
  for (int kc = 0; kc < 32; kc++){
    float4 xa = *reinterpret_cast<const float4*>(xp + kc * 32);
    float4 xb = *reinterpret_cast<const float4*>(xp + kc * 32 + 4);
    bf16x8 a;
    a[0] = (short)f2bf(xa.x); a[1] = (short)f2bf(xa.y);
    a[2] = (short)f2bf(xa.z); a[3] = (short)f2bf(xa.w);
    a[4] = (short)f2bf(xb.x); a[5] = (short)f2bf(xb.y);
    a[6] = (short)f2bf(xb.z); a[7] = (short)f2bf(xb.w);
    bf16x8 b0 = *reinterpret_cast<const bf16x8*>(&Vb[((size_t)( 0 + kc) * 64 + lane) * 8]);
    bf16x8 b1 = *reinterpret_cast<const bf16x8*>(&Vb[((size_t)(32 + kc) * 64 + lane) * 8]);
    bf16x8 b2 = *reinterpret_cast<const bf16x8*>(&Vb[((size_t)(64 + kc) * 64 + lane) * 8]);
    ac0 = __builtin_amdgcn_mfma_f32_16x16x32_bf16(a, b0, ac0, 0, 0, 0);
    ac1 = __builtin_amdgcn_mfma_f32_16x16x32_bf16(a, b1, ac1, 0, 0, 0);
    ac2 = __builtin_amdgcn_mfma_f32_16x16x32_bf16(a, b2, ac2, 0, 0, 0);
  }
  #pragma unroll
  for (int r = 0; r < 4; r++){
    int n = n0 + ks * 4 + r;
    Z[(size_t)n * ZS_ +  0 + row] = ac0[r];
    Z[(size_t)n * ZS_ + 16 + row] = ac1[r];
    Z[(size_t)n * ZS_ + 32 + row] = ac2[r];
  }
}

// ---------- layer-1 edge softmax (no max-shift: exactly equivalent) ----------
__global__ void edge_exp1(const int* __restrict__ ei, const float* __restrict__ Z,
                          float* __restrict__ expv, float* __restrict__ den1){
  int t = blockIdx.x * blockDim.x + threadIdx.x;
  if (t >= ET_ * H_) return;
  int e = t >> 3, h = t & 7;
  int s = eSRC(ei, e), d = eDST(ei, e);
  float lg = lrelu(Z[(size_t)s * ZS_ + h] + Z[(size_t)d * ZS_ + 8 + h]);
  float ev = expf(lg);
  expv[e * 8 + h] = ev;
  atomicAdd(&den1[d * 8 + h], ev);
}

// ---------- aggregate z over edges (per-edge atomics, 3 scalars per node) ----------
__global__ void agg_z(const int* __restrict__ ei, const float* __restrict__ Z,
                      const float* __restrict__ expv, const float* __restrict__ den1,
                      float* __restrict__ s0a, float* __restrict__ s1a,
                      float* __restrict__ sda){
  int e = blockIdx.x * blockDim.x + threadIdx.x;
  if (e >= ET_) return;
  int s = eSRC(ei, e), d = eDST(ei, e);
  float4 ev0 = *reinterpret_cast<const float4*>(expv + e * 8);
  float4 ev1 = *reinterpret_cast<const float4*>(expv + e * 8 + 4);
  float4 dn0 = *reinterpret_cast<const float4*>(den1 + d * 8);
  float4 dn1 = *reinterpret_cast<const float4*>(den1 + d * 8 + 4);
  float al[8];
  al[0] = ev0.x / (dn0.x + 1e-16f); al[1] = ev0.y / (dn0.y + 1e-16f);
  al[2] = ev0.z / (dn0.z + 1e-16f); al[3] = ev0.w / (dn0.w + 1e-16f);
  al[4] = ev1.x / (dn1.x + 1e-16f); al[5] = ev1.y / (dn1.y + 1e-16f);
  al[6] = ev1.z / (dn1.z + 1e-16f); al[7] = ev1.w / (dn1.w + 1e-16f);
  const float* zp = Z + (size_t)s * ZS_;
  float4 z0a = *reinterpret_cast<const float4*>(zp + 16);
  float4 z0b = *reinterpret_cast<const float4*>(zp + 20);
  float4 z1a = *reinterpret_cast<const float4*>(zp + 24);
  float4 z1b = *reinterpret_cast<const float4*>(zp + 28);
  float4 zda = *reinterpret_cast<const float4*>(zp + 32);
  float4 zdb = *reinterpret_cast<const float4*>(zp + 36);
  float p0 = al[0]*z0a.x + al[1]*z0a.y + al[2]*z0a.z + al[3]*z0a.w
           + al[4]*z0b.x + al[5]*z0b.y + al[6]*z0b.z + al[7]*z0b.w;
  float p1 = al[0]*z1a.x + al[1]*z1a.y + al[2]*z1a.z + al[3]*z1a.w
           + al[4]*z1b.x + al[5]*z1b.y + al[6]*z1b.z + al[7]*z1b.w;
  float pd = al[0]*zda.x + al[1]*zda.y + al[2]*zda.z + al[3]*zda.w
           + al[4]*zdb.x + al[5]*zdb.y + al[6]*zdb.z + al[7]*zdb.w;
  atomicAdd(&s0a[d], p0);
  atomicAdd(&s1a[d], p1);
  atomicAdd(&sda[d], pd);
}

// ---------- layer-2 per-node: add b1-constants, logits, init out with b2 ----------
__global__ void finalize_l2(const float* __restrict__ s0a, const float* __restrict__ s1a,
                            const float* __restrict__ sda, const float* __restrict__ cb,
                            const float* __restrict__ a2s, const float* __restrict__ b2,
                            float* __restrict__ s0b, float* __restrict__ s1b,
                            float* __restrict__ als2, float* __restrict__ ald2,
                            float* __restrict__ out){
  int n = blockIdx.x * blockDim.x + threadIdx.x;
  if (n >= N_) return;
  float v0 = s0a[n] + cb[0], v1 = s1a[n] + cb[1], vd = sda[n] + cb[2];
  s0b[n] = v0; s1b[n] = v1;
  als2[n] = v0 * a2s[0] + v1 * a2s[1];
  ald2[n] = vd;
  out[2 * n] = b2[0]; out[2 * n + 1] = b2[1];
}

// ---------- layer-2 edge softmax ----------
__global__ void edge_exp2(const int* __restrict__ ei, const float* __restrict__ als2,
                          const float* __restrict__ ald2, float* __restrict__ expv2,
                          float* __restrict__ den2){
  int e = blockIdx.x * blockDim.x + threadIdx.x;
  if (e >= ET_) return;
  int s = eSRC(ei, e), d = eDST(ei, e);
  float ev = expf(lrelu(als2[s] + ald2[d]));
  expv2[e] = ev;
  atomicAdd(&den2[d], ev);
}

// ---------- layer-2 aggregation -> output (per-edge atomics) ----------
__global__ void aggregate2(const int* __restrict__ ei, const float* __restrict__ expv2,
                           const float* __restrict__ den2, const float* __restrict__ s0b,
                           const float* __restrict__ s1b, float* __restrict__ out){
  int e = blockIdx.x * blockDim.x + threadIdx.x;
  if (e >= ET_) return;
  int s = eSRC(ei, e), d = eDST(ei, e);
  float a = expv2[e] / (den2[d] + 1e-16f);
  atomicAdd(&out[2 * d],     a * s0b[s]);
  atomicAdd(&out[2 * d + 1], a * s1b[s]);
}

// ---------- host ----------
extern "C" void kernel_launch(void* const* d_in, const int* in_sizes, int n_in,
                              void* d_out, int out_size, void* d_ws, size_t ws_size,
                              hipStream_t stream){
  const float* x   = (const float*)d_in[0];
  const int*   ei  = (const int*)  d_in[1];
  const float* W1s = (const float*)d_in[2];
  const float* W1d = (const float*)d_in[3];
  const float* a1s = (const float*)d_in[4];
  const float* a1d = (const float*)d_in[5];
  const float* b1  = (const float*)d_in[6];
  const float* W2s = (const float*)d_in[7];
  const float* W2d = (const float*)d_in[8];
  const float* a2s = (const float*)d_in[9];
  const float* a2d = (const float*)d_in[10];
  const float* b2  = (const float*)d_in[11];
  float* out = (float*)d_out;

  char* p = (char*)d_ws;
  auto alloc = [&](size_t bytes) -> void* {
    void* r = (void*)p;
    p += (bytes + 255) & ~(size_t)255;
    return r;
  };
  unsigned short* Vb = (unsigned short*)alloc((size_t)3 * 32 * 64 * 8 * 2); // 96 KB
  float* wd2   = (float*)alloc((size_t)F_ * 4);
  float* cb    = (float*)alloc(256);
  float* Z     = (float*)alloc((size_t)N_ * ZS_ * 4);      // 3 MB
  float* expv1 = (float*)alloc((size_t)ET_ * H_ * 4);      // 2.6 MB
  float* den1  = (float*)alloc((size_t)N_ * H_ * 4);
  float* s0a   = (float*)alloc((size_t)N_ * 4);
  float* s1a   = (float*)alloc((size_t)N_ * 4);
  float* sda   = (float*)alloc((size_t)N_ * 4);
  float* s0b   = (float*)alloc((size_t)N_ * 4);
  float* s1b   = (float*)alloc((size_t)N_ * 4);
  float* als2  = (float*)alloc((size_t)N_ * 4);
  float* ald2  = (float*)alloc((size_t)N_ * 4);
  float* den2  = (float*)alloc((size_t)N_ * 4);
  float* expv2 = (float*)alloc((size_t)ET_ * 4);

  init_all<<<dim3(N_ * H_ / 256), dim3(256), 0, stream>>>(den1, den2, s0a, s1a, sda,
                                                          (unsigned*)Vb);
  build_wd2<<<dim3(F_ / 256), dim3(256), 0, stream>>>(W2d, a2d, wd2);
  build_cb<<<dim3(1), dim3(256), 0, stream>>>(b1, W2s, wd2, cb);
  build_V<<<dim3(D_ * H_ / 4), dim3(256), 0, stream>>>(W1s, W1d, a1s, a1d, W2s, wd2, Vb);

  node_mfma<<<dim3(N_ / 16), dim3(64), 0, stream>>>(x, Vb, Z);

  edge_exp1<<<dim3(ET_ * H_ / 256), dim3(256), 0, stream>>>(ei, Z, expv1, den1);
  agg_z<<<dim3(ET_ / 256), dim3(256), 0, stream>>>(ei, Z, expv1, den1, s0a, s1a, sda);

  finalize_l2<<<dim3(N_ / 256), dim3(256), 0, stream>>>(s0a, s1a, sda, cb, a2s, b2,
                                                        s0b, s1b, als2, ald2, out);
  edge_exp2<<<dim3(ET_ / 256), dim3(256), 0, stream>>>(ei, als2, ald2, expv2, den2);
  aggregate2<<<dim3(ET_ / 256), dim3(256), 0, stream>>>(ei, expv2, den2, s0b, s1b, out);
}

// Round 6
// 74.772 us; speedup vs baseline: 31.9606x; 1.0813x over previous
//
#include <hip/hip_runtime.h>
#include <cstdint>
#include <cstddef>

#define DEV __device__ __forceinline__

typedef __attribute__((ext_vector_type(8))) short bf16x8;
typedef __attribute__((ext_vector_type(4))) float f32x4;

constexpr int N_  = 16384;
constexpr int D_  = 1024;
constexpr int E_  = 65536;
constexpr int ET_ = E_ + N_;   // edges incl. self loops
constexpr int H_  = 8;
constexpr int C_  = 512;
constexpr int F_  = 4096;      // H_*C_
constexpr int ZS_ = 48;        // [al_s 0..7 | al_d 8..15 | z0 16..23 | z1 24..31 | zd 32..39 | pad]
constexpr int KSPLIT = 2;

// ---------- helpers ----------
DEV unsigned short f2bf(float f){
  unsigned u = __float_as_uint(f);
  unsigned r = u + 0x7FFFu + ((u >> 16) & 1u); // RNE
  return (unsigned short)(r >> 16);
}
DEV float lrelu(float x){ return x >= 0.f ? x : 0.2f * x; }
DEV float waveSum(float v){
  #pragma unroll
  for (int o = 32; o > 0; o >>= 1) v += __shfl_xor(v, o);
  return v;
}
DEV int eSRC(const int* ei, int e){ return e < E_ ? ei[e]      : e - E_; }
DEV int eDST(const int* ei, int e){ return e < E_ ? ei[E_ + e] : e - E_; }

// ---------- kernel 1: zero contiguous region + build wd2 ----------
__global__ void init_all(uint4* __restrict__ zr, int n16,
                         const float* __restrict__ W2d, const float* __restrict__ a2d,
                         float* __restrict__ wd2){
  int i = blockIdx.x * blockDim.x + threadIdx.x;
  if (i < n16){ uint4 z = {0u,0u,0u,0u}; zr[i] = z; }
  if (i < F_) wd2[i] = W2d[i * 2] * a2d[0] + W2d[i * 2 + 1] * a2d[1];
}

// ---------- kernel 2: build V [1024 x 40 used cols] in MFMA-B-frag order + cb ----------
// col jj: jj=h: W1s_h.a1s[h] | 8+h: W1d_h.a1d[h] | 16+h: W1s_h.W2s[:,0]
//         24+h: W1s_h.W2s[:,1] | 32+h: W1s_h.wd2
// Vb[((tt*32+kc)*64 + ks*16 + j)*8 + i], tt=jj>>4, j=jj&15, kc=d>>5, ks=(d>>3)&3, i=d&7
__global__ __launch_bounds__(256) void build_Vcb(
    const float* __restrict__ W1s, const float* __restrict__ W1d,
    const float* __restrict__ a1s, const float* __restrict__ a1d,
    const float* __restrict__ W2s, const float* __restrict__ wd2,
    const float* __restrict__ b1,
    unsigned short* __restrict__ Vb, float* __restrict__ cb){
  int t = threadIdx.x;
  if (blockIdx.x == D_ * H_ / 4){
    // cb = (b1.W2s[:,0], b1.W2s[:,1], b1.wd2)
    __shared__ float red[3][4];
    int w = t >> 6, lane = t & 63;
    float p0 = 0.f, p1 = 0.f, pd = 0.f;
    for (int k = t; k < F_; k += 256){
      float b = b1[k];
      p0 += b * W2s[k * 2]; p1 += b * W2s[k * 2 + 1]; pd += b * wd2[k];
    }
    p0 = waveSum(p0); p1 = waveSum(p1); pd = waveSum(pd);
    if (lane == 0){ red[0][w] = p0; red[1][w] = p1; red[2][w] = pd; }
    __syncthreads();
    if (t == 0){
      cb[0] = red[0][0] + red[0][1] + red[0][2] + red[0][3];
      cb[1] = red[1][0] + red[1][1] + red[1][2] + red[1][3];
      cb[2] = red[2][0] + red[2][1] + red[2][2] + red[2][3];
    }
    return;
  }
  int id = blockIdx.x * 4 + (t >> 6);      // 0..8191
  int lane = t & 63;
  int d = id >> 3, h = id & 7;
  float sa = 0.f, sb = 0.f, s0 = 0.f, s1 = 0.f, sd = 0.f;
  #pragma unroll
  for (int i = 0; i < C_ / 64; i++){
    int c = i * 64 + lane;
    int gc = h * C_ + c;
    float ws  = W1s[(size_t)d * F_ + gc];
    float wdv = W1d[(size_t)d * F_ + gc];
    sa += ws * a1s[gc]; sb += wdv * a1d[gc];
    float2 w2 = *reinterpret_cast<const float2*>(W2s + (size_t)gc * 2);
    s0 += ws * w2.x; s1 += ws * w2.y; sd += ws * wd2[gc];
  }
  sa = waveSum(sa); sb = waveSum(sb);
  s0 = waveSum(s0); s1 = waveSum(s1); sd = waveSum(sd);
  if (lane == 0){
    int kc = d >> 5, ks = (d >> 3) & 3, ii = d & 7;
    auto put = [&](int jj, float v){
      int tt = jj >> 4, j = jj & 15;
      Vb[((size_t)(tt * 32 + kc) * 64 + ks * 16 + j) * 8 + ii] = f2bf(v);
    };
    put(h, sa); put(8 + h, sb); put(16 + h, s0); put(24 + h, s1); put(32 + h, sd);
  }
}

// ---------- kernel 3: Z[n][0..47] += x[n] @ V (half-K per wave, K-split x2) ----------
__global__ __launch_bounds__(64) void node_mfma(const float* __restrict__ X,
                                                const unsigned short* __restrict__ Vb,
                                                float* __restrict__ Z){
  int lane = threadIdx.x;
  int n0 = blockIdx.x * 16;
  int kh = blockIdx.y;                       // 0..KSPLIT-1
  int row = lane & 15, ks = lane >> 4;
  f32x4 ac0 = {0.f,0.f,0.f,0.f}, ac1 = ac0, ac2 = ac0;
  const float* xp = X + (size_t)(n0 + row) * D_ + ks * 8;
  constexpr int KC = 32 / KSPLIT;
  #pragma unroll 2
  for (int kk = 0; kk < KC; kk++){
    int kc = kh * KC + kk;
    float4 xa = *reinterpret_cast<const float4*>(xp + kc * 32);
    float4 xb = *reinterpret_cast<const float4*>(xp + kc * 32 + 4);
    bf16x8 a;
    a[0] = (short)f2bf(xa.x); a[1] = (short)f2bf(xa.y);
    a[2] = (short)f2bf(xa.z); a[3] = (short)f2bf(xa.w);
    a[4] = (short)f2bf(xb.x); a[5] = (short)f2bf(xb.y);
    a[6] = (short)f2bf(xb.z); a[7] = (short)f2bf(xb.w);
    bf16x8 b0 = *reinterpret_cast<const bf16x8*>(&Vb[((size_t)( 0 + kc) * 64 + lane) * 8]);
    bf16x8 b1 = *reinterpret_cast<const bf16x8*>(&Vb[((size_t)(32 + kc) * 64 + lane) * 8]);
    bf16x8 b2 = *reinterpret_cast<const bf16x8*>(&Vb[((size_t)(64 + kc) * 64 + lane) * 8]);
    ac0 = __builtin_amdgcn_mfma_f32_16x16x32_bf16(a, b0, ac0, 0, 0, 0);
    ac1 = __builtin_amdgcn_mfma_f32_16x16x32_bf16(a, b1, ac1, 0, 0, 0);
    ac2 = __builtin_amdgcn_mfma_f32_16x16x32_bf16(a, b2, ac2, 0, 0, 0);
  }
  #pragma unroll
  for (int r = 0; r < 4; r++){
    int n = n0 + ks * 4 + r;
    atomicAdd(&Z[(size_t)n * ZS_ +  0 + row], ac0[r]);
    atomicAdd(&Z[(size_t)n * ZS_ + 16 + row], ac1[r]);
    atomicAdd(&Z[(size_t)n * ZS_ + 32 + row], ac2[r]);
  }
}

// ---------- kernel 4: layer-1 edge softmax numerators + denominators ----------
__global__ void edge_exp1(const int* __restrict__ ei, const float* __restrict__ Z,
                          float* __restrict__ expv, float* __restrict__ den1){
  int t = blockIdx.x * blockDim.x + threadIdx.x;
  if (t >= ET_ * H_) return;
  int e = t >> 3, h = t & 7;
  int s = eSRC(ei, e), d = eDST(ei, e);
  float lg = lrelu(Z[(size_t)s * ZS_ + h] + Z[(size_t)d * ZS_ + 8 + h]);
  float ev = expf(lg);
  expv[e * 8 + h] = ev;
  atomicAdd(&den1[d * 8 + h], ev);
}

// ---------- kernel 5: aggregate z over edges ----------
__global__ void agg_z(const int* __restrict__ ei, const float* __restrict__ Z,
                      const float* __restrict__ expv, const float* __restrict__ den1,
                      float* __restrict__ s0a, float* __restrict__ s1a,
                      float* __restrict__ sda){
  int e = blockIdx.x * blockDim.x + threadIdx.x;
  if (e >= ET_) return;
  int s = eSRC(ei, e), d = eDST(ei, e);
  float4 ev0 = *reinterpret_cast<const float4*>(expv + e * 8);
  float4 ev1 = *reinterpret_cast<const float4*>(expv + e * 8 + 4);
  float4 dn0 = *reinterpret_cast<const float4*>(den1 + d * 8);
  float4 dn1 = *reinterpret_cast<const float4*>(den1 + d * 8 + 4);
  float al[8];
  al[0] = ev0.x / (dn0.x + 1e-16f); al[1] = ev0.y / (dn0.y + 1e-16f);
  al[2] = ev0.z / (dn0.z + 1e-16f); al[3] = ev0.w / (dn0.w + 1e-16f);
  al[4] = ev1.x / (dn1.x + 1e-16f); al[5] = ev1.y / (dn1.y + 1e-16f);
  al[6] = ev1.z / (dn1.z + 1e-16f); al[7] = ev1.w / (dn1.w + 1e-16f);
  const float* zp = Z + (size_t)s * ZS_;
  float4 z0a = *reinterpret_cast<const float4*>(zp + 16);
  float4 z0b = *reinterpret_cast<const float4*>(zp + 20);
  float4 z1a = *reinterpret_cast<const float4*>(zp + 24);
  float4 z1b = *reinterpret_cast<const float4*>(zp + 28);
  float4 zda = *reinterpret_cast<const float4*>(zp + 32);
  float4 zdb = *reinterpret_cast<const float4*>(zp + 36);
  float p0 = al[0]*z0a.x + al[1]*z0a.y + al[2]*z0a.z + al[3]*z0a.w
           + al[4]*z0b.x + al[5]*z0b.y + al[6]*z0b.z + al[7]*z0b.w;
  float p1 = al[0]*z1a.x + al[1]*z1a.y + al[2]*z1a.z + al[3]*z1a.w
           + al[4]*z1b.x + al[5]*z1b.y + al[6]*z1b.z + al[7]*z1b.w;
  float pd = al[0]*zda.x + al[1]*zda.y + al[2]*zda.z + al[3]*zda.w
           + al[4]*zdb.x + al[5]*zdb.y + al[6]*zdb.z + al[7]*zdb.w;
  atomicAdd(&s0a[d], p0);
  atomicAdd(&s1a[d], p1);
  atomicAdd(&sda[d], pd);
}

// ---------- kernel 6: layer-2 edge softmax (logits inline) + out init ----------
__global__ void edge_exp2(const int* __restrict__ ei, const float* __restrict__ s0a,
                          const float* __restrict__ s1a, const float* __restrict__ sda,
                          const float* __restrict__ cb, const float* __restrict__ a2s,
                          const float* __restrict__ b2,
                          float* __restrict__ expv2, float* __restrict__ den2,
                          float* __restrict__ out){
  int e = blockIdx.x * blockDim.x + threadIdx.x;
  if (e >= ET_) return;
  int s = eSRC(ei, e), d = eDST(ei, e);
  float als = (s0a[s] + cb[0]) * a2s[0] + (s1a[s] + cb[1]) * a2s[1];
  float ald = sda[d] + cb[2];
  float ev = expf(lrelu(als + ald));
  expv2[e] = ev;
  atomicAdd(&den2[d], ev);
  if (e < N_){ out[2 * e] = b2[0]; out[2 * e + 1] = b2[1]; }
}

// ---------- kernel 7: layer-2 aggregation -> output ----------
__global__ void aggregate2(const int* __restrict__ ei, const float* __restrict__ expv2,
                           const float* __restrict__ den2, const float* __restrict__ s0a,
                           const float* __restrict__ s1a, const float* __restrict__ cb,
                           float* __restrict__ out){
  int e = blockIdx.x * blockDim.x + threadIdx.x;
  if (e >= ET_) return;
  int s = eSRC(ei, e), d = eDST(ei, e);
  float a = expv2[e] / (den2[d] + 1e-16f);
  atomicAdd(&out[2 * d],     a * (s0a[s] + cb[0]));
  atomicAdd(&out[2 * d + 1], a * (s1a[s] + cb[1]));
}

// ---------- host ----------
extern "C" void kernel_launch(void* const* d_in, const int* in_sizes, int n_in,
                              void* d_out, int out_size, void* d_ws, size_t ws_size,
                              hipStream_t stream){
  const float* x   = (const float*)d_in[0];
  const int*   ei  = (const int*)  d_in[1];
  const float* W1s = (const float*)d_in[2];
  const float* W1d = (const float*)d_in[3];
  const float* a1s = (const float*)d_in[4];
  const float* a1d = (const float*)d_in[5];
  const float* b1  = (const float*)d_in[6];
  const float* W2s = (const float*)d_in[7];
  const float* W2d = (const float*)d_in[8];
  const float* a2s = (const float*)d_in[9];
  const float* a2d = (const float*)d_in[10];
  const float* b2  = (const float*)d_in[11];
  float* out = (float*)d_out;

  char* p = (char*)d_ws;
  auto alloc = [&](size_t bytes) -> void* {
    void* r = (void*)p;
    p += (bytes + 255) & ~(size_t)255;
    return r;
  };
  // ---- contiguous zero region: [Vb, Z, den1, den2, s0a, s1a, sda] ----
  unsigned short* Vb = (unsigned short*)alloc((size_t)3 * 32 * 64 * 8 * 2); // 96 KB
  float* Z     = (float*)alloc((size_t)N_ * ZS_ * 4);      // 3 MB
  float* den1  = (float*)alloc((size_t)N_ * H_ * 4);
  float* den2  = (float*)alloc((size_t)N_ * 4);
  float* s0a   = (float*)alloc((size_t)N_ * 4);
  float* s1a   = (float*)alloc((size_t)N_ * 4);
  float* sda   = (float*)alloc((size_t)N_ * 4);
  // ---- end zero region ----
  float* wd2   = (float*)alloc((size_t)F_ * 4);
  float* cb    = (float*)alloc(256);
  float* expv1 = (float*)alloc((size_t)ET_ * H_ * 4);      // 2.6 MB
  float* expv2 = (float*)alloc((size_t)ET_ * 4);

  size_t zrBytes = (size_t)((char*)wd2 - (char*)Vb);
  int n16 = (int)(zrBytes / 16);
  int g1 = (int)((((n16 > F_) ? n16 : F_) + 255) / 256);

  init_all<<<dim3(g1), dim3(256), 0, stream>>>((uint4*)Vb, n16, W2d, a2d, wd2);
  build_Vcb<<<dim3(D_ * H_ / 4 + 1), dim3(256), 0, stream>>>(W1s, W1d, a1s, a1d,
                                                             W2s, wd2, b1, Vb, cb);
  node_mfma<<<dim3(N_ / 16, KSPLIT), dim3(64), 0, stream>>>(x, Vb, Z);
  edge_exp1<<<dim3(ET_ * H_ / 256), dim3(256), 0, stream>>>(ei, Z, expv1, den1);
  agg_z<<<dim3(ET_ / 256), dim3(256), 0, stream>>>(ei, Z, expv1, den1, s0a, s1a, sda);
  edge_exp2<<<dim3(ET_ / 256), dim3(256), 0, stream>>>(ei, s0a, s1a, sda, cb, a2s, b2,
                                                       expv2, den2, out);
  aggregate2<<<dim3(ET_ / 256), dim3(256), 0, stream>>>(ei, expv2, den2, s0a, s1a, cb, out);
}